// Round 15
// baseline (256.715 us; speedup 1.0000x reference)
//
#include <hip/hip_runtime.h>
#include <hip/hip_bf16.h>
#include <hip/hip_fp16.h>

// VSSBlock: B=2 H=64 W=64 C=192 DM=384 N=16 R=12 K=4 L=4096
// R23 (on R22 base, 221.5us): packed-fp32 (v_pk_fma_f32 / v_pk_mul_f32) inner loops in
//     scan0/scan1/combine — pow16 as 8 packed muls, h-update 16 packed ops (was 32),
//     y-dot 8 packed (was 16). Halves VALU issue slots in the scan hot loops; loads,
//     registers, and structure unchanged. Everything else identical to R22.

typedef __attribute__((ext_vector_type(8))) short short8;     // 8 bf16 = 4 VGPRs
typedef __attribute__((ext_vector_type(4))) float floatx4;    // fp32 accum frag
typedef __attribute__((ext_vector_type(2))) float floatx2;    // packed fp32 pair

__device__ __forceinline__ floatx2 pk_fma(floatx2 a, floatx2 b, floatx2 c) {
  floatx2 d;
  asm("v_pk_fma_f32 %0, %1, %2, %3" : "=v"(d) : "v"(a), "v"(b), "v"(c));
  return d;
}
__device__ __forceinline__ floatx2 pk_mul(floatx2 a, floatx2 b) {
  floatx2 d;
  asm("v_pk_mul_f32 %0, %1, %2" : "=v"(d) : "v"(a), "v"(b));
  return d;
}
// pws2[i] = (r^(2i+1), r^(2i+2)) via pws2[i] = pws2[i-1] * (r^2, r^2)
__device__ __forceinline__ void pow16_pk(float r, floatx2* pws2) {
  float r2 = r * r;
  floatx2 r2v = {r2, r2};
  pws2[0] = floatx2{r, r2};
  #pragma unroll
  for (int i = 1; i < 8; i++) pws2[i] = pk_mul(pws2[i - 1], r2v);
}

// ---------------- fused: LN (pre-norm, eps 1e-6) -> bf16  +  weight pack ----------------
__global__ __launch_bounds__(256) void k_lnpackw(const float* __restrict__ in,
                                                 const float* __restrict__ g,
                                                 const float* __restrict__ be,
                                                 __hip_bfloat16* __restrict__ out,
                                                 const float* __restrict__ ipw,
                                                 const float* __restrict__ xpw,
                                                 const float* __restrict__ opw,
                                                 __hip_bfloat16* __restrict__ Wt1,
                                                 __hip_bfloat16* __restrict__ Wt2,
                                                 __hip_bfloat16* __restrict__ Wt3) {
  int bid = blockIdx.x;
  if (bid < 2048) {                 // LayerNorm: 4 rows/block
    int row = bid * 4 + (threadIdx.x >> 6);
    int lane = threadIdx.x & 63;
    const float* x = in + (long)row * 192;
    float v0 = x[lane], v1 = x[lane + 64], v2 = x[lane + 128];
    float s = v0 + v1 + v2;
    float s2 = v0 * v0 + v1 * v1 + v2 * v2;
    #pragma unroll
    for (int o = 32; o > 0; o >>= 1) { s += __shfl_xor(s, o); s2 += __shfl_xor(s2, o); }
    float mu = s * (1.f / 192.f);
    float var = s2 * (1.f / 192.f) - mu * mu;
    float r = rsqrtf(var + 1e-6f);
    __hip_bfloat16* op = out + (long)row * 192;
    op[lane]       = __float2bfloat16((v0 - mu) * r * g[lane]       + be[lane]);
    op[lane + 64]  = __float2bfloat16((v1 - mu) * r * g[lane + 64]  + be[lane + 64]);
    op[lane + 128] = __float2bfloat16((v2 - mu) * r * g[lane + 128] + be[lane + 128]);
  } else {                          // weight pack
    int idx = (bid - 2048) * 256 + threadIdx.x;
    if (idx < 147456) {                       // Wt1[n][k] = ipw[k][n]
      int n = idx / 192, k = idx - n * 192;
      Wt1[idx] = __float2bfloat16(ipw[(long)k * 768 + n]);
    } else if (idx < 147456 + 73728) {        // Wt2[j][d]
      int t = idx - 147456;
      int j = t / 384;
      float v = (j < 176) ? xpw[t] : 0.f;
      Wt2[t] = __float2bfloat16(v);
    } else if (idx < 147456 + 73728 + 73728) {// Wt3[n][k] = opw[k][n]
      int t = idx - 147456 - 73728;
      int n = t / 384, k = t - n * 384;
      Wt3[t] = __float2bfloat16(opw[(long)k * 192 + n]);
    }
  }
}

// direction map (involutions): pixel p <-> scan position l
__device__ __forceinline__ int inv_dir(int k, int p) {
  int pt = ((p & 63) << 6) | (p >> 6);
  if (k == 0) return p;
  if (k == 1) return pt;
  if (k == 2) return 4095 - p;
  return 4095 - pt;
}
__device__ __forceinline__ int dir_pix(int k, int l) { return inv_dir(k, l); }

// ---------------- bf16 MFMA GEMM: 64xTN tile, BK=64, XOR-swizzled LDS ----------------
template <int EPI, int TN>
__global__ __launch_bounds__(256) void k_gemm_mfma(const __hip_bfloat16* __restrict__ A,
                                                   const __hip_bfloat16* __restrict__ Bt,
                                                   const float* __restrict__ Res,
                                                   float* __restrict__ Co,
                                                   __hip_bfloat16* __restrict__ CoB,
                                                   __hip_bfloat16* __restrict__ Co2B,
                                                   float* __restrict__ dtsS,
                                                   float* __restrict__ BCs,
                                                   int M, int N, int Kk) {
  constexpr int NI = TN / 32;
  __shared__ __align__(16) short As[64 * 64];
  __shared__ __align__(16) short Bs[TN * 64];
  int tid = threadIdx.x;
  int wave = tid >> 6, lane = tid & 63;
  int mlane = lane & 15, quad = lane >> 4;
  int row0 = blockIdx.y * 64, col0 = blockIdx.x * TN;
  int wr = wave & 1, wc = wave >> 1;
  floatx4 acc[2][NI];
  #pragma unroll
  for (int mi = 0; mi < 2; mi++)
    #pragma unroll
    for (int ni = 0; ni < NI; ni++) acc[mi][ni] = (floatx4){0.f, 0.f, 0.f, 0.f};

  for (int k0 = 0; k0 < Kk; k0 += 64) {
    #pragma unroll
    for (int c = tid; c < 512; c += 256) {
      int r = c >> 3, j = c & 7;
      *(float4*)&As[r * 64 + ((j ^ (r & 7)) << 3)] =
          *(const float4*)&A[(long)(row0 + r) * Kk + k0 + j * 8];
    }
    #pragma unroll
    for (int c = tid; c < TN * 8; c += 256) {
      int r = c >> 3, j = c & 7;
      *(float4*)&Bs[r * 64 + ((j ^ (r & 7)) << 3)] =
          *(const float4*)&Bt[(long)(col0 + r) * Kk + k0 + j * 8];
    }
    __syncthreads();
    short8 af[2][2], bf[NI][2];
    #pragma unroll
    for (int mi = 0; mi < 2; mi++) {
      int r = wr * 32 + mi * 16 + mlane;
      #pragma unroll
      for (int kk = 0; kk < 2; kk++) {
        int jx = (kk * 4 + quad) ^ (r & 7);
        af[mi][kk] = *(const short8*)&As[r * 64 + jx * 8];
      }
    }
    #pragma unroll
    for (int ni = 0; ni < NI; ni++) {
      int rn = wc * (TN / 2) + ni * 16 + mlane;
      #pragma unroll
      for (int kk = 0; kk < 2; kk++) {
        int jx = (kk * 4 + quad) ^ (rn & 7);
        bf[ni][kk] = *(const short8*)&Bs[rn * 64 + jx * 8];
      }
    }
    #pragma unroll
    for (int kk = 0; kk < 2; kk++)
      #pragma unroll
      for (int mi = 0; mi < 2; mi++)
        #pragma unroll
        for (int ni = 0; ni < NI; ni++)
          acc[mi][ni] = __builtin_amdgcn_mfma_f32_16x16x32_bf16(af[mi][kk], bf[ni][kk],
                                                                acc[mi][ni], 0, 0, 0);
    __syncthreads();
  }
  // C/D layout: col=lane&15, row=quad*4+reg  [m89-verified]
  #pragma unroll
  for (int mi = 0; mi < 2; mi++) {
    #pragma unroll
    for (int ni = 0; ni < NI; ni++) {
      int cc = col0 + wc * (TN / 2) + ni * 16 + mlane;
      #pragma unroll
      for (int i = 0; i < 4; i++) {
        int rr = row0 + wr * 32 + mi * 16 + quad * 4 + i;
        float v = acc[mi][ni][i];
        if (EPI == 1) {
          Co[(long)rr * N + cc] = v + Res[(long)rr * N + cc];
        } else if (EPI == 2) {
          if (cc < 384) CoB[(long)rr * 384 + cc] = __float2bfloat16(v);
          else          Co2B[(long)rr * 384 + (cc - 384)] = __float2bfloat16(v);
        } else {  // EPI == 3: pixel-order split; B at 0..15, C at 16..31 of BCs row
          if (cc < 176) {
            int k4 = (cc >= 132) ? 3 : (cc >= 88) ? 2 : (cc >= 44) ? 1 : 0;
            int c = cc - k4 * 44;
            int b = rr >> 12, p = rr & 4095;
            long lbase = ((long)((b << 2) + k4) << 12) + p;   // pixel order
            if (c < 12) dtsS[lbase * 12 + c] = v;
            else        BCs[lbase * 32 + (c - 12)] = v;
          }
        }
      }
    }
  }
}

// ---------------- depthwise 3x3 conv + bias + SiLU; 2x4 pixels, d-paired ----------------
__global__ __launch_bounds__(192) void k_conv(const __hip_bfloat16* __restrict__ xbufB,
                                              const float* __restrict__ cw,
                                              const float* __restrict__ cb,
                                              __hip_bfloat16* __restrict__ xcb) {
  int blk = blockIdx.x;            // 1024: b(2) x hgroup(32) x wgroup(16)
  int wg = blk & 15, hg = (blk >> 4) & 31, b = blk >> 9;
  int h0 = hg * 2, w0 = wg * 4;
  int d0 = threadIdx.x * 2;        // channel pair d0, d0+1
  float wt0[9], wt1[9];
  #pragma unroll
  for (int i = 0; i < 9; i++) { wt0[i] = cw[(long)d0 * 9 + i]; wt1[i] = cw[(long)(d0 + 1) * 9 + i]; }
  float2 bias = *(const float2*)&cb[d0];
  float v0[4][6], v1[4][6];
  #pragma unroll
  for (int r = 0; r < 4; r++) {
    int hh = h0 + r - 1;
    bool rok = (hh >= 0) && (hh < 64);
    #pragma unroll
    for (int c = 0; c < 6; c++) {
      int ww = w0 + c - 1;
      bool ok = rok && (ww >= 0) && (ww < 64);
      unsigned uv = ok ? *(const unsigned*)&xbufB[((long)(b << 12) + (hh << 6) + ww) * 384 + d0] : 0u;
      v0[r][c] = __uint_as_float(uv << 16);
      v1[r][c] = __uint_as_float(uv & 0xffff0000u);
    }
  }
  #pragma unroll
  for (int i = 0; i < 2; i++) {
    #pragma unroll
    for (int j = 0; j < 4; j++) {
      float a0 = bias.x, a1 = bias.y;
      #pragma unroll
      for (int r = 0; r < 3; r++)
        #pragma unroll
        for (int c = 0; c < 3; c++) {
          a0 += v0[i + r][j + c] * wt0[r * 3 + c];
          a1 += v1[i + r][j + c] * wt1[r * 3 + c];
        }
      float s0 = a0 / (1.f + __expf(-a0));
      float s1 = a1 / (1.f + __expf(-a1));
      __hip_bfloat16 pr[2];
      pr[0] = __float2bfloat16(s0);
      pr[1] = __float2bfloat16(s1);
      *(unsigned*)&xcb[((long)(b << 12) + ((h0 + i) << 6) + (w0 + j)) * 384 + d0] = *(unsigned*)pr;
    }
  }
}

// powers: pws[n] = r^(n+1), log-depth pairing (scalar fallback path)
__device__ __forceinline__ void pow16(float r, float* pws) {
  pws[0] = r;
  #pragma unroll
  for (int n = 1; n < 16; n++) {
    int m = n + 1, c = (m + 1) / 2, f = m - c;
    pws[n] = pws[c - 1] * pws[f - 1];
  }
}

// ---------------- scan pass 0 (+dt fused): 128 segments x 32 steps; packed fp32 ----------------
__global__ __launch_bounds__(384) void k_scan0(
    const float* __restrict__ dtsS, const float* __restrict__ BCs,
    const __hip_bfloat16* __restrict__ xcb,
    const float* __restrict__ A_logs, const float* __restrict__ dt_w,
    const float* __restrict__ dt_b,
    __half* __restrict__ dpre, __half* __restrict__ EbH, float* __restrict__ Dend) {
  int bid = blockIdx.x;
  int s = bid & 127, bk = bid >> 7;
  int k = bk & 3, b = bk >> 2;
  int d = threadIdx.x;
  float w[12];
  const float* dwp = dt_w + ((long)(k * 384) + d) * 12;
  #pragma unroll
  for (int r = 0; r < 12; r++) w[r] = dwp[r];
  float db = dt_b[k * 384 + d];
  const float* al = A_logs + ((long)(k * 384) + d) * 16;
  bool pw = true;
  float av[16];
  #pragma unroll
  for (int n = 0; n < 16; n++) {
    float a = __expf(al[n]);
    av[n] = -a;
    pw = pw && (fabsf(a - (float)(n + 1)) < 1e-3f);
  }
  long bpk = (long)bk << 12;
  long bpix = (long)(b << 12);
  float cum = 0.f;

  if (pw) {
    floatx2 h2[8];
    #pragma unroll
    for (int i = 0; i < 8; i++) h2[i] = floatx2{0.f, 0.f};
    #pragma unroll 4
    for (int t = 0; t < 32; t++) {
      int p = dir_pix(k, s * 32 + t);
      const float4* dq = (const float4*)(dtsS + (bpk + p) * 12);
      float4 q0 = dq[0], q1 = dq[1], q2 = dq[2];
      float x = db + q0.x * w[0] + q0.y * w[1] + q0.z * w[2] + q0.w * w[3]
                   + q1.x * w[4] + q1.y * w[5] + q1.z * w[6] + q1.w * w[7]
                   + q2.x * w[8] + q2.y * w[9] + q2.z * w[10] + q2.w * w[11];
      float e = __expf(x);
      float delta = (x > 15.f) ? x : __logf(1.f + e);
      dpre[(bpk + p) * 384 + d] = __float2half(delta);
      float u = __bfloat162float(xcb[(bpix + p) * 384 + d]);
      cum += delta;
      float du = delta * u;
      floatx2 dud = {du, du};
      float rr = __expf(-delta);
      floatx2 pws2[8]; pow16_pk(rr, pws2);
      const float4* Bq = (const float4*)(BCs + (bpk + p) * 32);
      float4 b0 = Bq[0], b1 = Bq[1], b2 = Bq[2], b3 = Bq[3];
      floatx2 Bl2[8] = {{b0.x, b0.y}, {b0.z, b0.w}, {b1.x, b1.y}, {b1.z, b1.w},
                        {b2.x, b2.y}, {b2.z, b2.w}, {b3.x, b3.y}, {b3.z, b3.w}};
      #pragma unroll
      for (int i = 0; i < 8; i++) h2[i] = pk_fma(pws2[i], h2[i], pk_mul(dud, Bl2[i]));
    }
    long g = (long)bk * 128 + s;
    __half2* Ep = (__half2*)(EbH + g * 6144 + (long)d * 16);
    #pragma unroll
    for (int i = 0; i < 8; i++) {
      __half2 hv;
      hv.x = __float2half(h2[i].x);
      hv.y = __float2half(h2[i].y);
      Ep[i] = hv;
    }
    Dend[g * 384 + d] = cum;
  } else {
    float h[16];
    #pragma unroll
    for (int n = 0; n < 16; n++) h[n] = 0.f;
    for (int t = 0; t < 32; t++) {
      int p = dir_pix(k, s * 32 + t);
      const float4* dq = (const float4*)(dtsS + (bpk + p) * 12);
      float4 q0 = dq[0], q1 = dq[1], q2 = dq[2];
      float x = db + q0.x * w[0] + q0.y * w[1] + q0.z * w[2] + q0.w * w[3]
                   + q1.x * w[4] + q1.y * w[5] + q1.z * w[6] + q1.w * w[7]
                   + q2.x * w[8] + q2.y * w[9] + q2.z * w[10] + q2.w * w[11];
      float e = __expf(x);
      float delta = (x > 15.f) ? x : __logf(1.f + e);
      dpre[(bpk + p) * 384 + d] = __float2half(delta);
      float u = __bfloat162float(xcb[(bpix + p) * 384 + d]);
      cum += delta;
      float du = delta * u;
      const float4* Bq = (const float4*)(BCs + (bpk + p) * 32);
      float4 b0 = Bq[0], b1 = Bq[1], b2 = Bq[2], b3 = Bq[3];
      float Bl[16] = {b0.x, b0.y, b0.z, b0.w, b1.x, b1.y, b1.z, b1.w,
                      b2.x, b2.y, b2.z, b2.w, b3.x, b3.y, b3.z, b3.w};
      #pragma unroll
      for (int n = 0; n < 16; n++) {
        float dA = __expf(delta * av[n]);
        h[n] = dA * h[n] + du * Bl[n];
      }
    }
    long g = (long)bk * 128 + s;
    __half2* Ep = (__half2*)(EbH + g * 6144 + (long)d * 16);
    #pragma unroll
    for (int n = 0; n < 8; n++) {
      __half2 hv;
      hv.x = __float2half(h[2 * n]);
      hv.y = __float2half(h[2 * n + 1]);
      Ep[n] = hv;
    }
    Dend[g * 384 + d] = cum;
  }
}

// ---------------- combine: Kogge-Stone over 128 segments; packed fp32 rescale ----------------
__global__ __launch_bounds__(128) void k_combine(__half* __restrict__ EbH,
                                                 const float* __restrict__ Dend,
                                                 const float* __restrict__ A_logs) {
  int bid = blockIdx.x;            // bk*384 + d, 3072 blocks
  int bk = bid / 384;
  int d = bid - bk * 384;
  int k = bk & 3;
  int s = threadIdx.x;             // segment 0..127
  const float* al = A_logs + ((long)(k * 384) + d) * 16;
  bool pw = true;
  float av[16];
  #pragma unroll
  for (int n = 0; n < 16; n++) {
    float a = __expf(al[n]);
    av[n] = -a;
    pw = pw && (fabsf(a - (float)(n + 1)) < 1e-3f);
  }

  long ebase = ((long)bk * 128 + s) * 6144 + (long)d * 16;
  floatx2 e2[8];
  {
    const __half2* Ein = (const __half2*)(EbH + ebase);
    #pragma unroll
    for (int n = 0; n < 8; n++) {
      __half2 hv = Ein[n];
      e2[n] = floatx2{__half2float(hv.x), __half2float(hv.y)};
    }
  }
  float sig = Dend[((long)bk * 128 + s) * 384 + d];

  __shared__ float sSig[128];
  __shared__ __align__(8) float sEf[128][16];
  sSig[s] = sig;
  #pragma unroll
  for (int n = 0; n < 8; n++) *(floatx2*)&sEf[s][2 * n] = e2[n];
  __syncthreads();

  for (int o = 1; o < 128; o <<= 1) {
    float ps = 0.f;
    floatx2 pe2[8];
    bool act = (s >= o);
    if (act) {
      ps = sSig[s - o];
      #pragma unroll
      for (int n = 0; n < 8; n++) pe2[n] = *(floatx2*)&sEf[s - o][2 * n];
    }
    __syncthreads();
    if (act) {
      if (pw) {
        float rc = __expf(-sig);
        floatx2 pwr2[8]; pow16_pk(rc, pwr2);   // pwr2[i] = exp(av*sig) pairs
        #pragma unroll
        for (int n = 0; n < 8; n++) e2[n] = pk_fma(pwr2[n], pe2[n], e2[n]);
      } else {
        #pragma unroll
        for (int n = 0; n < 8; n++) {
          e2[n].x += __expf(av[2 * n] * sig) * pe2[n].x;
          e2[n].y += __expf(av[2 * n + 1] * sig) * pe2[n].y;
        }
      }
      sig += ps;
      sSig[s] = sig;
      #pragma unroll
      for (int n = 0; n < 8; n++) *(floatx2*)&sEf[s][2 * n] = e2[n];
    }
    __syncthreads();
  }

  floatx2 ho2[8];
  if (s == 0) {
    #pragma unroll
    for (int n = 0; n < 8; n++) ho2[n] = floatx2{0.f, 0.f};
  } else {
    #pragma unroll
    for (int n = 0; n < 8; n++) ho2[n] = *(floatx2*)&sEf[s - 1][2 * n];
  }
  __half2* Eo = (__half2*)(EbH + ebase);
  #pragma unroll
  for (int n = 0; n < 8; n++) {
    __half2 hv;
    hv.x = __float2half(ho2[n].x);
    hv.y = __float2half(ho2[n].y);
    Eo[n] = hv;
  }
}

// ---------------- scan pass 1: recurrence from h_in (fp16 EbH); packed fp32 ----------------
// ATOMIC=0: store y bf16 into per-direction plane ybufB. ATOMIC=1: fp32 atomicAdd ysum.
template <int ATOMIC>
__global__ __launch_bounds__(384) void k_scan1(
    const __half* __restrict__ dpre, const float* __restrict__ BCs,
    const __hip_bfloat16* __restrict__ xcb,
    const float* __restrict__ A_logs, const __half* __restrict__ EbH,
    __hip_bfloat16* __restrict__ ybufB, float* __restrict__ ysum) {
  int bid = blockIdx.x;
  int s = bid & 127, bk = bid >> 7;
  int k = bk & 3, b = bk >> 2;
  int d = threadIdx.x;
  const float* al = A_logs + ((long)(k * 384) + d) * 16;
  bool pw = true;
  float av[16];
  #pragma unroll
  for (int n = 0; n < 16; n++) {
    float a = __expf(al[n]);
    av[n] = -a;
    pw = pw && (fabsf(a - (float)(n + 1)) < 1e-3f);
  }
  long bpk = (long)bk << 12;
  long bpix = (long)(b << 12);

  if (pw) {
    floatx2 h2[8];
    {
      const __half2* hp = (const __half2*)(EbH + ((long)bk * 128 + s) * 6144 + (long)d * 16);
      #pragma unroll
      for (int n = 0; n < 8; n++) {
        __half2 hv = hp[n];
        h2[n] = floatx2{__half2float(hv.x), __half2float(hv.y)};
      }
    }
    #pragma unroll 4
    for (int t = 0; t < 32; t++) {
      int p = dir_pix(k, s * 32 + t);
      float delta = __half2float(dpre[(bpk + p) * 384 + d]);
      float u = __bfloat162float(xcb[(bpix + p) * 384 + d]);
      float du = delta * u;
      floatx2 dud = {du, du};
      float rr = __expf(-delta);
      floatx2 pws2[8]; pow16_pk(rr, pws2);
      const float4* Bq = (const float4*)(BCs + (bpk + p) * 32);
      float4 b0 = Bq[0], b1 = Bq[1], b2 = Bq[2], b3 = Bq[3];
      floatx2 Bl2[8] = {{b0.x, b0.y}, {b0.z, b0.w}, {b1.x, b1.y}, {b1.z, b1.w},
                        {b2.x, b2.y}, {b2.z, b2.w}, {b3.x, b3.y}, {b3.z, b3.w}};
      const float4* Cq = Bq + 4;
      float4 c0 = Cq[0], c1 = Cq[1], c2 = Cq[2], c3 = Cq[3];
      floatx2 Cl2[8] = {{c0.x, c0.y}, {c0.z, c0.w}, {c1.x, c1.y}, {c1.z, c1.w},
                        {c2.x, c2.y}, {c2.z, c2.w}, {c3.x, c3.y}, {c3.z, c3.w}};
      floatx2 y2 = {0.f, 0.f};
      #pragma unroll
      for (int i = 0; i < 8; i++) {
        h2[i] = pk_fma(pws2[i], h2[i], pk_mul(dud, Bl2[i]));
        y2 = pk_fma(h2[i], Cl2[i], y2);
      }
      float y = y2.x + y2.y;
      if (ATOMIC) atomicAdd(&ysum[(bpix + p) * 384 + d], y);
      else        ybufB[(bpk + p) * 384 + d] = __float2bfloat16(y);
    }
  } else {
    float h[16];
    {
      const __half2* hp = (const __half2*)(EbH + ((long)bk * 128 + s) * 6144 + (long)d * 16);
      #pragma unroll
      for (int n = 0; n < 8; n++) {
        __half2 hv = hp[n];
        h[2 * n]     = __half2float(hv.x);
        h[2 * n + 1] = __half2float(hv.y);
      }
    }
    for (int t = 0; t < 32; t++) {
      int p = dir_pix(k, s * 32 + t);
      float delta = __half2float(dpre[(bpk + p) * 384 + d]);
      float u = __bfloat162float(xcb[(bpix + p) * 384 + d]);
      float du = delta * u;
      const float4* Bq = (const float4*)(BCs + (bpk + p) * 32);
      float4 b0 = Bq[0], b1 = Bq[1], b2 = Bq[2], b3 = Bq[3];
      float Bl[16] = {b0.x, b0.y, b0.z, b0.w, b1.x, b1.y, b1.z, b1.w,
                      b2.x, b2.y, b2.z, b2.w, b3.x, b3.y, b3.z, b3.w};
      const float4* Cq = Bq + 4;
      float4 c0 = Cq[0], c1 = Cq[1], c2 = Cq[2], c3 = Cq[3];
      float Cl[16] = {c0.x, c0.y, c0.z, c0.w, c1.x, c1.y, c1.z, c1.w,
                      c2.x, c2.y, c2.z, c2.w, c3.x, c3.y, c3.z, c3.w};
      float y = 0.f;
      #pragma unroll
      for (int n = 0; n < 16; n++) {
        float dA = __expf(delta * av[n]);
        h[n] = dA * h[n] + du * Bl[n];
        y += h[n] * Cl[n];
      }
      if (ATOMIC) atomicAdd(&ysum[(bpix + p) * 384 + d], y);
      else        ybufB[(bpk + p) * 384 + d] = __float2bfloat16(y);
    }
  }
}

// ---------------- merge (d-paired, 192 thr): y + D-skip + out-LN + silu(z) -> bf16 ----------------
template <int GATHER>
__global__ __launch_bounds__(192) void k_merge(const __hip_bfloat16* __restrict__ yinB,
                                               const float* __restrict__ yinF,
                                               const __hip_bfloat16* __restrict__ xcb,
                                               const __hip_bfloat16* __restrict__ zbufB,
                                               const float* __restrict__ Ds,
                                               const float* __restrict__ g,
                                               const float* __restrict__ be,
                                               __hip_bfloat16* __restrict__ yactb) {
  int row = blockIdx.x;
  int d0 = threadIdx.x * 2;
  float v0, v1;
  if (GATHER) {
    int b = row >> 12, p = row & 4095;
    long base = ((long)(b << 2) << 12) + p;  // plane (b*4+k)*4096 + p
    v0 = 0.f; v1 = 0.f;
    #pragma unroll
    for (int pl = 0; pl < 4; pl++) {
      unsigned uv = *(const unsigned*)&yinB[(base + pl * 4096) * 384 + d0];
      v0 += __uint_as_float(uv << 16);
      v1 += __uint_as_float(uv & 0xffff0000u);
    }
  } else {
    float2 vv = *(const float2*)&yinF[(long)row * 384 + d0];
    v0 = vv.x; v1 = vv.y;
  }
  float2 ds0 = *(const float2*)&Ds[d0];
  float2 ds1 = *(const float2*)&Ds[384 + d0];
  float2 ds2 = *(const float2*)&Ds[768 + d0];
  float2 ds3 = *(const float2*)&Ds[1152 + d0];
  float sd0 = ds0.x + ds1.x + ds2.x + ds3.x;
  float sd1 = ds0.y + ds1.y + ds2.y + ds3.y;
  {
    unsigned uv = *(const unsigned*)&xcb[(long)row * 384 + d0];
    v0 += __uint_as_float(uv << 16) * sd0;
    v1 += __uint_as_float(uv & 0xffff0000u) * sd1;
  }
  float s1 = v0 + v1, s2 = v0 * v0 + v1 * v1;
  #pragma unroll
  for (int o = 32; o > 0; o >>= 1) { s1 += __shfl_xor(s1, o); s2 += __shfl_xor(s2, o); }
  __shared__ float r1[3], r2[3];
  int wv = threadIdx.x >> 6;
  if ((threadIdx.x & 63) == 0) { r1[wv] = s1; r2[wv] = s2; }
  __syncthreads();
  float S1 = r1[0] + r1[1] + r1[2];
  float S2 = r2[0] + r2[1] + r2[2];
  float mu = S1 * (1.f / 384.f);
  float var = S2 * (1.f / 384.f) - mu * mu;
  float rr = rsqrtf(var + 1e-5f);
  float2 gg = *(const float2*)&g[d0];
  float2 bb = *(const float2*)&be[d0];
  float yn0 = (v0 - mu) * rr * gg.x + bb.x;
  float yn1 = (v1 - mu) * rr * gg.y + bb.y;
  unsigned uz = *(const unsigned*)&zbufB[(long)row * 384 + d0];
  float z0 = __uint_as_float(uz << 16);
  float z1 = __uint_as_float(uz & 0xffff0000u);
  float sg0 = z0 / (1.f + __expf(-z0));
  float sg1 = z1 / (1.f + __expf(-z1));
  __hip_bfloat16 pr[2];
  pr[0] = __float2bfloat16(yn0 * sg0);
  pr[1] = __float2bfloat16(yn1 * sg1);
  *(unsigned*)&yactb[(long)row * 384 + d0] = *(unsigned*)pr;
}

extern "C" void kernel_launch(void* const* d_in, const int* in_sizes, int n_in,
                              void* d_out, int out_size, void* d_ws, size_t ws_size,
                              hipStream_t stream) {
  const float* input      = (const float*)d_in[0];
  const float* norm_g     = (const float*)d_in[1];
  const float* norm_b     = (const float*)d_in[2];
  const float* in_proj_w  = (const float*)d_in[3];
  const float* conv_w     = (const float*)d_in[4];
  const float* conv_b     = (const float*)d_in[5];
  const float* x_proj_w   = (const float*)d_in[6];
  const float* dt_w       = (const float*)d_in[7];
  const float* dt_b       = (const float*)d_in[8];
  const float* A_logs     = (const float*)d_in[9];
  const float* Ds         = (const float*)d_in[10];
  const float* out_norm_g = (const float*)d_in[11];
  const float* out_norm_b = (const float*)d_in[12];
  const float* out_proj_w = (const float*)d_in[13];
  float* out = (float*)d_out;

  // plane path total = 24,788,992 floats (~99 MB); atomic fallback = 21,643,264 (~87 MB)
  bool big = ws_size >= (size_t)24788992 * 4;

  float* ws = (float*)d_ws;
  long o = 0;
  __hip_bfloat16* xnb   = (__hip_bfloat16*)(ws + o); o += 786432;   // 8192x192 bf16
  __hip_bfloat16* xbufB = (__hip_bfloat16*)(ws + o); o += 1572864;  // 8192x384 bf16
  __hip_bfloat16* zbufB = (__hip_bfloat16*)(ws + o); o += 1572864;
  __hip_bfloat16* xcb   = (__hip_bfloat16*)(ws + o); o += 1572864;
  __hip_bfloat16* Wt1   = (__hip_bfloat16*)(ws + o); o += 73728;    // 768x192 bf16
  __hip_bfloat16* Wt2   = (__hip_bfloat16*)(ws + o); o += 36864;
  __hip_bfloat16* Wt3   = (__hip_bfloat16*)(ws + o); o += 36864;
  float* dtsS           = ws + o;                    o += 393216;   // (BK,p,12) pixel order
  float* BCs            = ws + o;                    o += 1048576;  // (BK,p,32): B|C interleaved
  __half* dpre          = (__half*)(ws + o);         o += 6291456;  // (BK,p,384) fp16 delta
  __half* EbH           = (__half*)(ws + o);         o += 3145728;  // (1024 segs, 6144) fp16
  float* Dend           = ws + o;                    o += 393216;   // (1024, 384) fp32
  __hip_bfloat16* ybufB = (__hip_bfloat16*)(ws + o);
  float* ysum           = ws + o;                    o += big ? 6291456 : 3145728;
  __hip_bfloat16* yactb = (__hip_bfloat16*)(ws + o); o += 1572864;

  k_lnpackw<<<dim3(3200), dim3(256), 0, stream>>>(input, norm_g, norm_b, xnb,
                                                  in_proj_w, x_proj_w, out_proj_w, Wt1, Wt2, Wt3);
  k_gemm_mfma<2, 192><<<dim3(4, 128), dim3(256), 0, stream>>>(xnb, Wt1, nullptr, nullptr, xbufB, zbufB,
                                                              nullptr, nullptr, 8192, 768, 192);
  k_conv<<<dim3(1024), dim3(192), 0, stream>>>(xbufB, conv_w, conv_b, xcb);
  k_gemm_mfma<3, 64><<<dim3(3, 128), dim3(256), 0, stream>>>(xcb, Wt2, nullptr, nullptr, nullptr, nullptr,
                                                             dtsS, BCs, 8192, 192, 384);
  k_scan0<<<dim3(1024), dim3(384), 0, stream>>>(dtsS, BCs, xcb, A_logs, dt_w, dt_b,
                                                dpre, EbH, Dend);
  k_combine<<<dim3(3072), dim3(128), 0, stream>>>(EbH, Dend, A_logs);
  if (big) {
    k_scan1<0><<<dim3(1024), dim3(384), 0, stream>>>(dpre, BCs, xcb, A_logs, EbH, ybufB, nullptr);
    k_merge<1><<<dim3(8192), dim3(192), 0, stream>>>(ybufB, nullptr, xcb, zbufB, Ds,
                                                     out_norm_g, out_norm_b, yactb);
  } else {
    hipMemsetAsync(ysum, 0, (size_t)3145728 * 4, stream);
    k_scan1<1><<<dim3(1024), dim3(384), 0, stream>>>(dpre, BCs, xcb, A_logs, EbH, nullptr, ysum);
    k_merge<0><<<dim3(8192), dim3(192), 0, stream>>>(nullptr, ysum, xcb, zbufB, Ds,
                                                     out_norm_g, out_norm_b, yactb);
  }
  k_gemm_mfma<1, 64><<<dim3(3, 128), dim3(256), 0, stream>>>(yactb, Wt3, input, out, nullptr, nullptr,
                                                             nullptr, nullptr, 8192, 192, 384);
}

// Round 16
// 230.572 us; speedup vs baseline: 1.1134x; 1.1134x over previous
//
#include <hip/hip_runtime.h>
#include <hip/hip_bf16.h>
#include <hip/hip_fp16.h>

// VSSBlock: B=2 H=64 W=64 C=192 DM=384 N=16 R=12 K=4 L=4096
// R24: R23's combine LDS layout [128][16] caused 1.9e7 bank conflicts (combine 10->47us).
//      Fix: sEf[128][18] (72B row stride: float2-aligned, bank-stride 18 -> 2-way = free).
//      Packed-fp32 scans kept (measured -2.4us in R23). Everything else = R22.

typedef __attribute__((ext_vector_type(8))) short short8;     // 8 bf16 = 4 VGPRs
typedef __attribute__((ext_vector_type(4))) float floatx4;    // fp32 accum frag
typedef __attribute__((ext_vector_type(2))) float floatx2;    // packed fp32 pair

__device__ __forceinline__ floatx2 pk_fma(floatx2 a, floatx2 b, floatx2 c) {
  floatx2 d;
  asm("v_pk_fma_f32 %0, %1, %2, %3" : "=v"(d) : "v"(a), "v"(b), "v"(c));
  return d;
}
__device__ __forceinline__ floatx2 pk_mul(floatx2 a, floatx2 b) {
  floatx2 d;
  asm("v_pk_mul_f32 %0, %1, %2" : "=v"(d) : "v"(a), "v"(b));
  return d;
}
// pws2[i] = (r^(2i+1), r^(2i+2)) via pws2[i] = pws2[i-1] * (r^2, r^2)
__device__ __forceinline__ void pow16_pk(float r, floatx2* pws2) {
  float r2 = r * r;
  floatx2 r2v = {r2, r2};
  pws2[0] = floatx2{r, r2};
  #pragma unroll
  for (int i = 1; i < 8; i++) pws2[i] = pk_mul(pws2[i - 1], r2v);
}

// ---------------- fused: LN (pre-norm, eps 1e-6) -> bf16  +  weight pack ----------------
__global__ __launch_bounds__(256) void k_lnpackw(const float* __restrict__ in,
                                                 const float* __restrict__ g,
                                                 const float* __restrict__ be,
                                                 __hip_bfloat16* __restrict__ out,
                                                 const float* __restrict__ ipw,
                                                 const float* __restrict__ xpw,
                                                 const float* __restrict__ opw,
                                                 __hip_bfloat16* __restrict__ Wt1,
                                                 __hip_bfloat16* __restrict__ Wt2,
                                                 __hip_bfloat16* __restrict__ Wt3) {
  int bid = blockIdx.x;
  if (bid < 2048) {                 // LayerNorm: 4 rows/block
    int row = bid * 4 + (threadIdx.x >> 6);
    int lane = threadIdx.x & 63;
    const float* x = in + (long)row * 192;
    float v0 = x[lane], v1 = x[lane + 64], v2 = x[lane + 128];
    float s = v0 + v1 + v2;
    float s2 = v0 * v0 + v1 * v1 + v2 * v2;
    #pragma unroll
    for (int o = 32; o > 0; o >>= 1) { s += __shfl_xor(s, o); s2 += __shfl_xor(s2, o); }
    float mu = s * (1.f / 192.f);
    float var = s2 * (1.f / 192.f) - mu * mu;
    float r = rsqrtf(var + 1e-6f);
    __hip_bfloat16* op = out + (long)row * 192;
    op[lane]       = __float2bfloat16((v0 - mu) * r * g[lane]       + be[lane]);
    op[lane + 64]  = __float2bfloat16((v1 - mu) * r * g[lane + 64]  + be[lane + 64]);
    op[lane + 128] = __float2bfloat16((v2 - mu) * r * g[lane + 128] + be[lane + 128]);
  } else {                          // weight pack
    int idx = (bid - 2048) * 256 + threadIdx.x;
    if (idx < 147456) {                       // Wt1[n][k] = ipw[k][n]
      int n = idx / 192, k = idx - n * 192;
      Wt1[idx] = __float2bfloat16(ipw[(long)k * 768 + n]);
    } else if (idx < 147456 + 73728) {        // Wt2[j][d]
      int t = idx - 147456;
      int j = t / 384;
      float v = (j < 176) ? xpw[t] : 0.f;
      Wt2[t] = __float2bfloat16(v);
    } else if (idx < 147456 + 73728 + 73728) {// Wt3[n][k] = opw[k][n]
      int t = idx - 147456 - 73728;
      int n = t / 384, k = t - n * 384;
      Wt3[t] = __float2bfloat16(opw[(long)k * 192 + n]);
    }
  }
}

// direction map (involutions): pixel p <-> scan position l
__device__ __forceinline__ int inv_dir(int k, int p) {
  int pt = ((p & 63) << 6) | (p >> 6);
  if (k == 0) return p;
  if (k == 1) return pt;
  if (k == 2) return 4095 - p;
  return 4095 - pt;
}
__device__ __forceinline__ int dir_pix(int k, int l) { return inv_dir(k, l); }

// ---------------- bf16 MFMA GEMM: 64xTN tile, BK=64, XOR-swizzled LDS ----------------
template <int EPI, int TN>
__global__ __launch_bounds__(256) void k_gemm_mfma(const __hip_bfloat16* __restrict__ A,
                                                   const __hip_bfloat16* __restrict__ Bt,
                                                   const float* __restrict__ Res,
                                                   float* __restrict__ Co,
                                                   __hip_bfloat16* __restrict__ CoB,
                                                   __hip_bfloat16* __restrict__ Co2B,
                                                   float* __restrict__ dtsS,
                                                   float* __restrict__ BCs,
                                                   int M, int N, int Kk) {
  constexpr int NI = TN / 32;
  __shared__ __align__(16) short As[64 * 64];
  __shared__ __align__(16) short Bs[TN * 64];
  int tid = threadIdx.x;
  int wave = tid >> 6, lane = tid & 63;
  int mlane = lane & 15, quad = lane >> 4;
  int row0 = blockIdx.y * 64, col0 = blockIdx.x * TN;
  int wr = wave & 1, wc = wave >> 1;
  floatx4 acc[2][NI];
  #pragma unroll
  for (int mi = 0; mi < 2; mi++)
    #pragma unroll
    for (int ni = 0; ni < NI; ni++) acc[mi][ni] = (floatx4){0.f, 0.f, 0.f, 0.f};

  for (int k0 = 0; k0 < Kk; k0 += 64) {
    #pragma unroll
    for (int c = tid; c < 512; c += 256) {
      int r = c >> 3, j = c & 7;
      *(float4*)&As[r * 64 + ((j ^ (r & 7)) << 3)] =
          *(const float4*)&A[(long)(row0 + r) * Kk + k0 + j * 8];
    }
    #pragma unroll
    for (int c = tid; c < TN * 8; c += 256) {
      int r = c >> 3, j = c & 7;
      *(float4*)&Bs[r * 64 + ((j ^ (r & 7)) << 3)] =
          *(const float4*)&Bt[(long)(col0 + r) * Kk + k0 + j * 8];
    }
    __syncthreads();
    short8 af[2][2], bf[NI][2];
    #pragma unroll
    for (int mi = 0; mi < 2; mi++) {
      int r = wr * 32 + mi * 16 + mlane;
      #pragma unroll
      for (int kk = 0; kk < 2; kk++) {
        int jx = (kk * 4 + quad) ^ (r & 7);
        af[mi][kk] = *(const short8*)&As[r * 64 + jx * 8];
      }
    }
    #pragma unroll
    for (int ni = 0; ni < NI; ni++) {
      int rn = wc * (TN / 2) + ni * 16 + mlane;
      #pragma unroll
      for (int kk = 0; kk < 2; kk++) {
        int jx = (kk * 4 + quad) ^ (rn & 7);
        bf[ni][kk] = *(const short8*)&Bs[rn * 64 + jx * 8];
      }
    }
    #pragma unroll
    for (int kk = 0; kk < 2; kk++)
      #pragma unroll
      for (int mi = 0; mi < 2; mi++)
        #pragma unroll
        for (int ni = 0; ni < NI; ni++)
          acc[mi][ni] = __builtin_amdgcn_mfma_f32_16x16x32_bf16(af[mi][kk], bf[ni][kk],
                                                                acc[mi][ni], 0, 0, 0);
    __syncthreads();
  }
  // C/D layout: col=lane&15, row=quad*4+reg  [m89-verified]
  #pragma unroll
  for (int mi = 0; mi < 2; mi++) {
    #pragma unroll
    for (int ni = 0; ni < NI; ni++) {
      int cc = col0 + wc * (TN / 2) + ni * 16 + mlane;
      #pragma unroll
      for (int i = 0; i < 4; i++) {
        int rr = row0 + wr * 32 + mi * 16 + quad * 4 + i;
        float v = acc[mi][ni][i];
        if (EPI == 1) {
          Co[(long)rr * N + cc] = v + Res[(long)rr * N + cc];
        } else if (EPI == 2) {
          if (cc < 384) CoB[(long)rr * 384 + cc] = __float2bfloat16(v);
          else          Co2B[(long)rr * 384 + (cc - 384)] = __float2bfloat16(v);
        } else {  // EPI == 3: pixel-order split; B at 0..15, C at 16..31 of BCs row
          if (cc < 176) {
            int k4 = (cc >= 132) ? 3 : (cc >= 88) ? 2 : (cc >= 44) ? 1 : 0;
            int c = cc - k4 * 44;
            int b = rr >> 12, p = rr & 4095;
            long lbase = ((long)((b << 2) + k4) << 12) + p;   // pixel order
            if (c < 12) dtsS[lbase * 12 + c] = v;
            else        BCs[lbase * 32 + (c - 12)] = v;
          }
        }
      }
    }
  }
}

// ---------------- depthwise 3x3 conv + bias + SiLU; 2x4 pixels, d-paired ----------------
__global__ __launch_bounds__(192) void k_conv(const __hip_bfloat16* __restrict__ xbufB,
                                              const float* __restrict__ cw,
                                              const float* __restrict__ cb,
                                              __hip_bfloat16* __restrict__ xcb) {
  int blk = blockIdx.x;            // 1024: b(2) x hgroup(32) x wgroup(16)
  int wg = blk & 15, hg = (blk >> 4) & 31, b = blk >> 9;
  int h0 = hg * 2, w0 = wg * 4;
  int d0 = threadIdx.x * 2;        // channel pair d0, d0+1
  float wt0[9], wt1[9];
  #pragma unroll
  for (int i = 0; i < 9; i++) { wt0[i] = cw[(long)d0 * 9 + i]; wt1[i] = cw[(long)(d0 + 1) * 9 + i]; }
  float2 bias = *(const float2*)&cb[d0];
  float v0[4][6], v1[4][6];
  #pragma unroll
  for (int r = 0; r < 4; r++) {
    int hh = h0 + r - 1;
    bool rok = (hh >= 0) && (hh < 64);
    #pragma unroll
    for (int c = 0; c < 6; c++) {
      int ww = w0 + c - 1;
      bool ok = rok && (ww >= 0) && (ww < 64);
      unsigned uv = ok ? *(const unsigned*)&xbufB[((long)(b << 12) + (hh << 6) + ww) * 384 + d0] : 0u;
      v0[r][c] = __uint_as_float(uv << 16);
      v1[r][c] = __uint_as_float(uv & 0xffff0000u);
    }
  }
  #pragma unroll
  for (int i = 0; i < 2; i++) {
    #pragma unroll
    for (int j = 0; j < 4; j++) {
      float a0 = bias.x, a1 = bias.y;
      #pragma unroll
      for (int r = 0; r < 3; r++)
        #pragma unroll
        for (int c = 0; c < 3; c++) {
          a0 += v0[i + r][j + c] * wt0[r * 3 + c];
          a1 += v1[i + r][j + c] * wt1[r * 3 + c];
        }
      float s0 = a0 / (1.f + __expf(-a0));
      float s1 = a1 / (1.f + __expf(-a1));
      __hip_bfloat16 pr[2];
      pr[0] = __float2bfloat16(s0);
      pr[1] = __float2bfloat16(s1);
      *(unsigned*)&xcb[((long)(b << 12) + ((h0 + i) << 6) + (w0 + j)) * 384 + d0] = *(unsigned*)pr;
    }
  }
}

// powers: pws[n] = r^(n+1), log-depth pairing (scalar fallback path)
__device__ __forceinline__ void pow16(float r, float* pws) {
  pws[0] = r;
  #pragma unroll
  for (int n = 1; n < 16; n++) {
    int m = n + 1, c = (m + 1) / 2, f = m - c;
    pws[n] = pws[c - 1] * pws[f - 1];
  }
}

// ---------------- scan pass 0 (+dt fused): 128 segments x 32 steps; packed fp32 ----------------
__global__ __launch_bounds__(384) void k_scan0(
    const float* __restrict__ dtsS, const float* __restrict__ BCs,
    const __hip_bfloat16* __restrict__ xcb,
    const float* __restrict__ A_logs, const float* __restrict__ dt_w,
    const float* __restrict__ dt_b,
    __half* __restrict__ dpre, __half* __restrict__ EbH, float* __restrict__ Dend) {
  int bid = blockIdx.x;
  int s = bid & 127, bk = bid >> 7;
  int k = bk & 3, b = bk >> 2;
  int d = threadIdx.x;
  float w[12];
  const float* dwp = dt_w + ((long)(k * 384) + d) * 12;
  #pragma unroll
  for (int r = 0; r < 12; r++) w[r] = dwp[r];
  float db = dt_b[k * 384 + d];
  const float* al = A_logs + ((long)(k * 384) + d) * 16;
  bool pw = true;
  float av[16];
  #pragma unroll
  for (int n = 0; n < 16; n++) {
    float a = __expf(al[n]);
    av[n] = -a;
    pw = pw && (fabsf(a - (float)(n + 1)) < 1e-3f);
  }
  long bpk = (long)bk << 12;
  long bpix = (long)(b << 12);
  float cum = 0.f;

  if (pw) {
    floatx2 h2[8];
    #pragma unroll
    for (int i = 0; i < 8; i++) h2[i] = floatx2{0.f, 0.f};
    #pragma unroll 4
    for (int t = 0; t < 32; t++) {
      int p = dir_pix(k, s * 32 + t);
      const float4* dq = (const float4*)(dtsS + (bpk + p) * 12);
      float4 q0 = dq[0], q1 = dq[1], q2 = dq[2];
      float x = db + q0.x * w[0] + q0.y * w[1] + q0.z * w[2] + q0.w * w[3]
                   + q1.x * w[4] + q1.y * w[5] + q1.z * w[6] + q1.w * w[7]
                   + q2.x * w[8] + q2.y * w[9] + q2.z * w[10] + q2.w * w[11];
      float e = __expf(x);
      float delta = (x > 15.f) ? x : __logf(1.f + e);
      dpre[(bpk + p) * 384 + d] = __float2half(delta);
      float u = __bfloat162float(xcb[(bpix + p) * 384 + d]);
      cum += delta;
      float du = delta * u;
      floatx2 dud = {du, du};
      float rr = __expf(-delta);
      floatx2 pws2[8]; pow16_pk(rr, pws2);
      const float4* Bq = (const float4*)(BCs + (bpk + p) * 32);
      float4 b0 = Bq[0], b1 = Bq[1], b2 = Bq[2], b3 = Bq[3];
      floatx2 Bl2[8] = {{b0.x, b0.y}, {b0.z, b0.w}, {b1.x, b1.y}, {b1.z, b1.w},
                        {b2.x, b2.y}, {b2.z, b2.w}, {b3.x, b3.y}, {b3.z, b3.w}};
      #pragma unroll
      for (int i = 0; i < 8; i++) h2[i] = pk_fma(pws2[i], h2[i], pk_mul(dud, Bl2[i]));
    }
    long g = (long)bk * 128 + s;
    __half2* Ep = (__half2*)(EbH + g * 6144 + (long)d * 16);
    #pragma unroll
    for (int i = 0; i < 8; i++) {
      __half2 hv;
      hv.x = __float2half(h2[i].x);
      hv.y = __float2half(h2[i].y);
      Ep[i] = hv;
    }
    Dend[g * 384 + d] = cum;
  } else {
    float h[16];
    #pragma unroll
    for (int n = 0; n < 16; n++) h[n] = 0.f;
    for (int t = 0; t < 32; t++) {
      int p = dir_pix(k, s * 32 + t);
      const float4* dq = (const float4*)(dtsS + (bpk + p) * 12);
      float4 q0 = dq[0], q1 = dq[1], q2 = dq[2];
      float x = db + q0.x * w[0] + q0.y * w[1] + q0.z * w[2] + q0.w * w[3]
                   + q1.x * w[4] + q1.y * w[5] + q1.z * w[6] + q1.w * w[7]
                   + q2.x * w[8] + q2.y * w[9] + q2.z * w[10] + q2.w * w[11];
      float e = __expf(x);
      float delta = (x > 15.f) ? x : __logf(1.f + e);
      dpre[(bpk + p) * 384 + d] = __float2half(delta);
      float u = __bfloat162float(xcb[(bpix + p) * 384 + d]);
      cum += delta;
      float du = delta * u;
      const float4* Bq = (const float4*)(BCs + (bpk + p) * 32);
      float4 b0 = Bq[0], b1 = Bq[1], b2 = Bq[2], b3 = Bq[3];
      float Bl[16] = {b0.x, b0.y, b0.z, b0.w, b1.x, b1.y, b1.z, b1.w,
                      b2.x, b2.y, b2.z, b2.w, b3.x, b3.y, b3.z, b3.w};
      #pragma unroll
      for (int n = 0; n < 16; n++) {
        float dA = __expf(delta * av[n]);
        h[n] = dA * h[n] + du * Bl[n];
      }
    }
    long g = (long)bk * 128 + s;
    __half2* Ep = (__half2*)(EbH + g * 6144 + (long)d * 16);
    #pragma unroll
    for (int n = 0; n < 8; n++) {
      __half2 hv;
      hv.x = __float2half(h[2 * n]);
      hv.y = __float2half(h[2 * n + 1]);
      Ep[n] = hv;
    }
    Dend[g * 384 + d] = cum;
  }
}

// ---------------- combine: Kogge-Stone over 128 segments; stride-18 LDS (2-way = free) ----------------
__global__ __launch_bounds__(128) void k_combine(__half* __restrict__ EbH,
                                                 const float* __restrict__ Dend,
                                                 const float* __restrict__ A_logs) {
  int bid = blockIdx.x;            // bk*384 + d, 3072 blocks
  int bk = bid / 384;
  int d = bid - bk * 384;
  int k = bk & 3;
  int s = threadIdx.x;             // segment 0..127
  const float* al = A_logs + ((long)(k * 384) + d) * 16;
  bool pw = true;
  float av[16];
  #pragma unroll
  for (int n = 0; n < 16; n++) {
    float a = __expf(al[n]);
    av[n] = -a;
    pw = pw && (fabsf(a - (float)(n + 1)) < 1e-3f);
  }

  long ebase = ((long)bk * 128 + s) * 6144 + (long)d * 16;
  floatx2 e2[8];
  {
    const __half2* Ein = (const __half2*)(EbH + ebase);
    #pragma unroll
    for (int n = 0; n < 8; n++) {
      __half2 hv = Ein[n];
      e2[n] = floatx2{__half2float(hv.x), __half2float(hv.y)};
    }
  }
  float sig = Dend[((long)bk * 128 + s) * 384 + d];

  __shared__ float sSig[128];
  __shared__ __align__(8) float sEf[128][18];   // stride 18 floats = 72B: 8B-aligned rows,
  sSig[s] = sig;                                 // bank stride 18 -> max 2-way (free, m136)
  #pragma unroll
  for (int n = 0; n < 8; n++) *(floatx2*)&sEf[s][2 * n] = e2[n];
  __syncthreads();

  for (int o = 1; o < 128; o <<= 1) {
    float ps = 0.f;
    floatx2 pe2[8];
    bool act = (s >= o);
    if (act) {
      ps = sSig[s - o];
      #pragma unroll
      for (int n = 0; n < 8; n++) pe2[n] = *(floatx2*)&sEf[s - o][2 * n];
    }
    __syncthreads();
    if (act) {
      if (pw) {
        float rc = __expf(-sig);
        floatx2 pwr2[8]; pow16_pk(rc, pwr2);   // pwr2[i] = exp(av*sig) pairs
        #pragma unroll
        for (int n = 0; n < 8; n++) e2[n] = pk_fma(pwr2[n], pe2[n], e2[n]);
      } else {
        #pragma unroll
        for (int n = 0; n < 8; n++) {
          e2[n].x += __expf(av[2 * n] * sig) * pe2[n].x;
          e2[n].y += __expf(av[2 * n + 1] * sig) * pe2[n].y;
        }
      }
      sig += ps;
      sSig[s] = sig;
      #pragma unroll
      for (int n = 0; n < 8; n++) *(floatx2*)&sEf[s][2 * n] = e2[n];
    }
    __syncthreads();
  }

  floatx2 ho2[8];
  if (s == 0) {
    #pragma unroll
    for (int n = 0; n < 8; n++) ho2[n] = floatx2{0.f, 0.f};
  } else {
    #pragma unroll
    for (int n = 0; n < 8; n++) ho2[n] = *(floatx2*)&sEf[s - 1][2 * n];
  }
  __half2* Eo = (__half2*)(EbH + ebase);
  #pragma unroll
  for (int n = 0; n < 8; n++) {
    __half2 hv;
    hv.x = __float2half(ho2[n].x);
    hv.y = __float2half(ho2[n].y);
    Eo[n] = hv;
  }
}

// ---------------- scan pass 1: recurrence from h_in (fp16 EbH); packed fp32 ----------------
// ATOMIC=0: store y bf16 into per-direction plane ybufB. ATOMIC=1: fp32 atomicAdd ysum.
template <int ATOMIC>
__global__ __launch_bounds__(384) void k_scan1(
    const __half* __restrict__ dpre, const float* __restrict__ BCs,
    const __hip_bfloat16* __restrict__ xcb,
    const float* __restrict__ A_logs, const __half* __restrict__ EbH,
    __hip_bfloat16* __restrict__ ybufB, float* __restrict__ ysum) {
  int bid = blockIdx.x;
  int s = bid & 127, bk = bid >> 7;
  int k = bk & 3, b = bk >> 2;
  int d = threadIdx.x;
  const float* al = A_logs + ((long)(k * 384) + d) * 16;
  bool pw = true;
  float av[16];
  #pragma unroll
  for (int n = 0; n < 16; n++) {
    float a = __expf(al[n]);
    av[n] = -a;
    pw = pw && (fabsf(a - (float)(n + 1)) < 1e-3f);
  }
  long bpk = (long)bk << 12;
  long bpix = (long)(b << 12);

  if (pw) {
    floatx2 h2[8];
    {
      const __half2* hp = (const __half2*)(EbH + ((long)bk * 128 + s) * 6144 + (long)d * 16);
      #pragma unroll
      for (int n = 0; n < 8; n++) {
        __half2 hv = hp[n];
        h2[n] = floatx2{__half2float(hv.x), __half2float(hv.y)};
      }
    }
    #pragma unroll 4
    for (int t = 0; t < 32; t++) {
      int p = dir_pix(k, s * 32 + t);
      float delta = __half2float(dpre[(bpk + p) * 384 + d]);
      float u = __bfloat162float(xcb[(bpix + p) * 384 + d]);
      float du = delta * u;
      floatx2 dud = {du, du};
      float rr = __expf(-delta);
      floatx2 pws2[8]; pow16_pk(rr, pws2);
      const float4* Bq = (const float4*)(BCs + (bpk + p) * 32);
      float4 b0 = Bq[0], b1 = Bq[1], b2 = Bq[2], b3 = Bq[3];
      floatx2 Bl2[8] = {{b0.x, b0.y}, {b0.z, b0.w}, {b1.x, b1.y}, {b1.z, b1.w},
                        {b2.x, b2.y}, {b2.z, b2.w}, {b3.x, b3.y}, {b3.z, b3.w}};
      const float4* Cq = Bq + 4;
      float4 c0 = Cq[0], c1 = Cq[1], c2 = Cq[2], c3 = Cq[3];
      floatx2 Cl2[8] = {{c0.x, c0.y}, {c0.z, c0.w}, {c1.x, c1.y}, {c1.z, c1.w},
                        {c2.x, c2.y}, {c2.z, c2.w}, {c3.x, c3.y}, {c3.z, c3.w}};
      floatx2 y2 = {0.f, 0.f};
      #pragma unroll
      for (int i = 0; i < 8; i++) {
        h2[i] = pk_fma(pws2[i], h2[i], pk_mul(dud, Bl2[i]));
        y2 = pk_fma(h2[i], Cl2[i], y2);
      }
      float y = y2.x + y2.y;
      if (ATOMIC) atomicAdd(&ysum[(bpix + p) * 384 + d], y);
      else        ybufB[(bpk + p) * 384 + d] = __float2bfloat16(y);
    }
  } else {
    float h[16];
    {
      const __half2* hp = (const __half2*)(EbH + ((long)bk * 128 + s) * 6144 + (long)d * 16);
      #pragma unroll
      for (int n = 0; n < 8; n++) {
        __half2 hv = hp[n];
        h[2 * n]     = __half2float(hv.x);
        h[2 * n + 1] = __half2float(hv.y);
      }
    }
    for (int t = 0; t < 32; t++) {
      int p = dir_pix(k, s * 32 + t);
      float delta = __half2float(dpre[(bpk + p) * 384 + d]);
      float u = __bfloat162float(xcb[(bpix + p) * 384 + d]);
      float du = delta * u;
      const float4* Bq = (const float4*)(BCs + (bpk + p) * 32);
      float4 b0 = Bq[0], b1 = Bq[1], b2 = Bq[2], b3 = Bq[3];
      float Bl[16] = {b0.x, b0.y, b0.z, b0.w, b1.x, b1.y, b1.z, b1.w,
                      b2.x, b2.y, b2.z, b2.w, b3.x, b3.y, b3.z, b3.w};
      const float4* Cq = Bq + 4;
      float4 c0 = Cq[0], c1 = Cq[1], c2 = Cq[2], c3 = Cq[3];
      float Cl[16] = {c0.x, c0.y, c0.z, c0.w, c1.x, c1.y, c1.z, c1.w,
                      c2.x, c2.y, c2.z, c2.w, c3.x, c3.y, c3.z, c3.w};
      float y = 0.f;
      #pragma unroll
      for (int n = 0; n < 16; n++) {
        float dA = __expf(delta * av[n]);
        h[n] = dA * h[n] + du * Bl[n];
        y += h[n] * Cl[n];
      }
      if (ATOMIC) atomicAdd(&ysum[(bpix + p) * 384 + d], y);
      else        ybufB[(bpk + p) * 384 + d] = __float2bfloat16(y);
    }
  }
}

// ---------------- merge (d-paired, 192 thr): y + D-skip + out-LN + silu(z) -> bf16 ----------------
template <int GATHER>
__global__ __launch_bounds__(192) void k_merge(const __hip_bfloat16* __restrict__ yinB,
                                               const float* __restrict__ yinF,
                                               const __hip_bfloat16* __restrict__ xcb,
                                               const __hip_bfloat16* __restrict__ zbufB,
                                               const float* __restrict__ Ds,
                                               const float* __restrict__ g,
                                               const float* __restrict__ be,
                                               __hip_bfloat16* __restrict__ yactb) {
  int row = blockIdx.x;
  int d0 = threadIdx.x * 2;
  float v0, v1;
  if (GATHER) {
    int b = row >> 12, p = row & 4095;
    long base = ((long)(b << 2) << 12) + p;  // plane (b*4+k)*4096 + p
    v0 = 0.f; v1 = 0.f;
    #pragma unroll
    for (int pl = 0; pl < 4; pl++) {
      unsigned uv = *(const unsigned*)&yinB[(base + pl * 4096) * 384 + d0];
      v0 += __uint_as_float(uv << 16);
      v1 += __uint_as_float(uv & 0xffff0000u);
    }
  } else {
    float2 vv = *(const float2*)&yinF[(long)row * 384 + d0];
    v0 = vv.x; v1 = vv.y;
  }
  float2 ds0 = *(const float2*)&Ds[d0];
  float2 ds1 = *(const float2*)&Ds[384 + d0];
  float2 ds2 = *(const float2*)&Ds[768 + d0];
  float2 ds3 = *(const float2*)&Ds[1152 + d0];
  float sd0 = ds0.x + ds1.x + ds2.x + ds3.x;
  float sd1 = ds0.y + ds1.y + ds2.y + ds3.y;
  {
    unsigned uv = *(const unsigned*)&xcb[(long)row * 384 + d0];
    v0 += __uint_as_float(uv << 16) * sd0;
    v1 += __uint_as_float(uv & 0xffff0000u) * sd1;
  }
  float s1 = v0 + v1, s2 = v0 * v0 + v1 * v1;
  #pragma unroll
  for (int o = 32; o > 0; o >>= 1) { s1 += __shfl_xor(s1, o); s2 += __shfl_xor(s2, o); }
  __shared__ float r1[3], r2[3];
  int wv = threadIdx.x >> 6;
  if ((threadIdx.x & 63) == 0) { r1[wv] = s1; r2[wv] = s2; }
  __syncthreads();
  float S1 = r1[0] + r1[1] + r1[2];
  float S2 = r2[0] + r2[1] + r2[2];
  float mu = S1 * (1.f / 384.f);
  float var = S2 * (1.f / 384.f) - mu * mu;
  float rr = rsqrtf(var + 1e-5f);
  float2 gg = *(const float2*)&g[d0];
  float2 bb = *(const float2*)&be[d0];
  float yn0 = (v0 - mu) * rr * gg.x + bb.x;
  float yn1 = (v1 - mu) * rr * gg.y + bb.y;
  unsigned uz = *(const unsigned*)&zbufB[(long)row * 384 + d0];
  float z0 = __uint_as_float(uz << 16);
  float z1 = __uint_as_float(uz & 0xffff0000u);
  float sg0 = z0 / (1.f + __expf(-z0));
  float sg1 = z1 / (1.f + __expf(-z1));
  __hip_bfloat16 pr[2];
  pr[0] = __float2bfloat16(yn0 * sg0);
  pr[1] = __float2bfloat16(yn1 * sg1);
  *(unsigned*)&yactb[(long)row * 384 + d0] = *(unsigned*)pr;
}

extern "C" void kernel_launch(void* const* d_in, const int* in_sizes, int n_in,
                              void* d_out, int out_size, void* d_ws, size_t ws_size,
                              hipStream_t stream) {
  const float* input      = (const float*)d_in[0];
  const float* norm_g     = (const float*)d_in[1];
  const float* norm_b     = (const float*)d_in[2];
  const float* in_proj_w  = (const float*)d_in[3];
  const float* conv_w     = (const float*)d_in[4];
  const float* conv_b     = (const float*)d_in[5];
  const float* x_proj_w   = (const float*)d_in[6];
  const float* dt_w       = (const float*)d_in[7];
  const float* dt_b       = (const float*)d_in[8];
  const float* A_logs     = (const float*)d_in[9];
  const float* Ds         = (const float*)d_in[10];
  const float* out_norm_g = (const float*)d_in[11];
  const float* out_norm_b = (const float*)d_in[12];
  const float* out_proj_w = (const float*)d_in[13];
  float* out = (float*)d_out;

  // plane path total = 24,788,992 floats (~99 MB); atomic fallback = 21,643,264 (~87 MB)
  bool big = ws_size >= (size_t)24788992 * 4;

  float* ws = (float*)d_ws;
  long o = 0;
  __hip_bfloat16* xnb   = (__hip_bfloat16*)(ws + o); o += 786432;   // 8192x192 bf16
  __hip_bfloat16* xbufB = (__hip_bfloat16*)(ws + o); o += 1572864;  // 8192x384 bf16
  __hip_bfloat16* zbufB = (__hip_bfloat16*)(ws + o); o += 1572864;
  __hip_bfloat16* xcb   = (__hip_bfloat16*)(ws + o); o += 1572864;
  __hip_bfloat16* Wt1   = (__hip_bfloat16*)(ws + o); o += 73728;    // 768x192 bf16
  __hip_bfloat16* Wt2   = (__hip_bfloat16*)(ws + o); o += 36864;
  __hip_bfloat16* Wt3   = (__hip_bfloat16*)(ws + o); o += 36864;
  float* dtsS           = ws + o;                    o += 393216;   // (BK,p,12) pixel order
  float* BCs            = ws + o;                    o += 1048576;  // (BK,p,32): B|C interleaved
  __half* dpre          = (__half*)(ws + o);         o += 6291456;  // (BK,p,384) fp16 delta
  __half* EbH           = (__half*)(ws + o);         o += 3145728;  // (1024 segs, 6144) fp16
  float* Dend           = ws + o;                    o += 393216;   // (1024, 384) fp32
  __hip_bfloat16* ybufB = (__hip_bfloat16*)(ws + o);
  float* ysum           = ws + o;                    o += big ? 6291456 : 3145728;
  __hip_bfloat16* yactb = (__hip_bfloat16*)(ws + o); o += 1572864;

  k_lnpackw<<<dim3(3200), dim3(256), 0, stream>>>(input, norm_g, norm_b, xnb,
                                                  in_proj_w, x_proj_w, out_proj_w, Wt1, Wt2, Wt3);
  k_gemm_mfma<2, 192><<<dim3(4, 128), dim3(256), 0, stream>>>(xnb, Wt1, nullptr, nullptr, xbufB, zbufB,
                                                              nullptr, nullptr, 8192, 768, 192);
  k_conv<<<dim3(1024), dim3(192), 0, stream>>>(xbufB, conv_w, conv_b, xcb);
  k_gemm_mfma<3, 64><<<dim3(3, 128), dim3(256), 0, stream>>>(xcb, Wt2, nullptr, nullptr, nullptr, nullptr,
                                                             dtsS, BCs, 8192, 192, 384);
  k_scan0<<<dim3(1024), dim3(384), 0, stream>>>(dtsS, BCs, xcb, A_logs, dt_w, dt_b,
                                                dpre, EbH, Dend);
  k_combine<<<dim3(3072), dim3(128), 0, stream>>>(EbH, Dend, A_logs);
  if (big) {
    k_scan1<0><<<dim3(1024), dim3(384), 0, stream>>>(dpre, BCs, xcb, A_logs, EbH, ybufB, nullptr);
    k_merge<1><<<dim3(8192), dim3(192), 0, stream>>>(ybufB, nullptr, xcb, zbufB, Ds,
                                                     out_norm_g, out_norm_b, yactb);
  } else {
    hipMemsetAsync(ysum, 0, (size_t)3145728 * 4, stream);
    k_scan1<1><<<dim3(1024), dim3(384), 0, stream>>>(dpre, BCs, xcb, A_logs, EbH, nullptr, ysum);
    k_merge<0><<<dim3(8192), dim3(192), 0, stream>>>(nullptr, ysum, xcb, zbufB, Ds,
                                                     out_norm_g, out_norm_b, yactb);
  }
  k_gemm_mfma<1, 64><<<dim3(3, 128), dim3(256), 0, stream>>>(yactb, Wt3, input, out, nullptr, nullptr,
                                                             nullptr, nullptr, 8192, 192, 384);
}

// Round 17
// 221.511 us; speedup vs baseline: 1.1589x; 1.0409x over previous
//
#include <hip/hip_runtime.h>
#include <hip/hip_bf16.h>
#include <hip/hip_fp16.h>

// VSSBlock: B=2 H=64 W=64 C=192 DM=384 N=16 R=12 K=4 L=4096
// R25: full revert of R23/R24 packed-fp32 scans (serial pow16_pk chain + asm scheduling
//      barriers cost +9us). Base = R22 (221.5us best). Micro-cuts: (1) EbH accessed as
//      2x float4 (was 8x half2) in scan0/combine/scan1; (2) merge's Ds-sum precomputed
//      once in k_lnpackw (sdsum[384]).

typedef __attribute__((ext_vector_type(8))) short short8;     // 8 bf16 = 4 VGPRs
typedef __attribute__((ext_vector_type(4))) float floatx4;    // fp32 accum frag

__device__ __forceinline__ void packE(const float* h, float4* o) {
  unsigned u[8];
  #pragma unroll
  for (int n = 0; n < 8; n++) {
    __half2 hv;
    hv.x = __float2half(h[2 * n]);
    hv.y = __float2half(h[2 * n + 1]);
    u[n] = *(unsigned*)&hv;
  }
  o[0] = *(float4*)&u[0];
  o[1] = *(float4*)&u[4];
}
__device__ __forceinline__ void unpackE(const float4* i, float* h) {
  float4 a = i[0], b = i[1];
  unsigned u[8];
  *(float4*)&u[0] = a;
  *(float4*)&u[4] = b;
  #pragma unroll
  for (int n = 0; n < 8; n++) {
    __half2 hv = *(__half2*)&u[n];
    h[2 * n]     = __half2float(hv.x);
    h[2 * n + 1] = __half2float(hv.y);
  }
}

// ---------------- fused: LN (pre-norm, eps 1e-6) -> bf16  +  weight pack + Ds-sum ----------------
__global__ __launch_bounds__(256) void k_lnpackw(const float* __restrict__ in,
                                                 const float* __restrict__ g,
                                                 const float* __restrict__ be,
                                                 __hip_bfloat16* __restrict__ out,
                                                 const float* __restrict__ ipw,
                                                 const float* __restrict__ xpw,
                                                 const float* __restrict__ opw,
                                                 const float* __restrict__ Ds,
                                                 __hip_bfloat16* __restrict__ Wt1,
                                                 __hip_bfloat16* __restrict__ Wt2,
                                                 __hip_bfloat16* __restrict__ Wt3,
                                                 float* __restrict__ sdsum) {
  int bid = blockIdx.x;
  if (bid < 2048) {                 // LayerNorm: 4 rows/block
    int row = bid * 4 + (threadIdx.x >> 6);
    int lane = threadIdx.x & 63;
    const float* x = in + (long)row * 192;
    float v0 = x[lane], v1 = x[lane + 64], v2 = x[lane + 128];
    float s = v0 + v1 + v2;
    float s2 = v0 * v0 + v1 * v1 + v2 * v2;
    #pragma unroll
    for (int o = 32; o > 0; o >>= 1) { s += __shfl_xor(s, o); s2 += __shfl_xor(s2, o); }
    float mu = s * (1.f / 192.f);
    float var = s2 * (1.f / 192.f) - mu * mu;
    float r = rsqrtf(var + 1e-6f);
    __hip_bfloat16* op = out + (long)row * 192;
    op[lane]       = __float2bfloat16((v0 - mu) * r * g[lane]       + be[lane]);
    op[lane + 64]  = __float2bfloat16((v1 - mu) * r * g[lane + 64]  + be[lane + 64]);
    op[lane + 128] = __float2bfloat16((v2 - mu) * r * g[lane + 128] + be[lane + 128]);
  } else {                          // weight pack + Ds-sum
    int idx = (bid - 2048) * 256 + threadIdx.x;
    if (idx < 147456) {                       // Wt1[n][k] = ipw[k][n]
      int n = idx / 192, k = idx - n * 192;
      Wt1[idx] = __float2bfloat16(ipw[(long)k * 768 + n]);
    } else if (idx < 147456 + 73728) {        // Wt2[j][d]
      int t = idx - 147456;
      int j = t / 384;
      float v = (j < 176) ? xpw[t] : 0.f;
      Wt2[t] = __float2bfloat16(v);
    } else if (idx < 147456 + 73728 + 73728) {// Wt3[n][k] = opw[k][n]
      int t = idx - 147456 - 73728;
      int n = t / 384, k = t - n * 384;
      Wt3[t] = __float2bfloat16(opw[(long)k * 192 + n]);
    } else if (idx < 147456 + 73728 + 73728 + 384) {
      int t = idx - 147456 - 73728 - 73728;
      sdsum[t] = Ds[t] + Ds[384 + t] + Ds[768 + t] + Ds[1152 + t];
    }
  }
}

// direction map (involutions): pixel p <-> scan position l
__device__ __forceinline__ int inv_dir(int k, int p) {
  int pt = ((p & 63) << 6) | (p >> 6);
  if (k == 0) return p;
  if (k == 1) return pt;
  if (k == 2) return 4095 - p;
  return 4095 - pt;
}
__device__ __forceinline__ int dir_pix(int k, int l) { return inv_dir(k, l); }

// ---------------- bf16 MFMA GEMM: 64xTN tile, BK=64, XOR-swizzled LDS ----------------
template <int EPI, int TN>
__global__ __launch_bounds__(256) void k_gemm_mfma(const __hip_bfloat16* __restrict__ A,
                                                   const __hip_bfloat16* __restrict__ Bt,
                                                   const float* __restrict__ Res,
                                                   float* __restrict__ Co,
                                                   __hip_bfloat16* __restrict__ CoB,
                                                   __hip_bfloat16* __restrict__ Co2B,
                                                   float* __restrict__ dtsS,
                                                   float* __restrict__ BCs,
                                                   int M, int N, int Kk) {
  constexpr int NI = TN / 32;
  __shared__ __align__(16) short As[64 * 64];
  __shared__ __align__(16) short Bs[TN * 64];
  int tid = threadIdx.x;
  int wave = tid >> 6, lane = tid & 63;
  int mlane = lane & 15, quad = lane >> 4;
  int row0 = blockIdx.y * 64, col0 = blockIdx.x * TN;
  int wr = wave & 1, wc = wave >> 1;
  floatx4 acc[2][NI];
  #pragma unroll
  for (int mi = 0; mi < 2; mi++)
    #pragma unroll
    for (int ni = 0; ni < NI; ni++) acc[mi][ni] = (floatx4){0.f, 0.f, 0.f, 0.f};

  for (int k0 = 0; k0 < Kk; k0 += 64) {
    #pragma unroll
    for (int c = tid; c < 512; c += 256) {
      int r = c >> 3, j = c & 7;
      *(float4*)&As[r * 64 + ((j ^ (r & 7)) << 3)] =
          *(const float4*)&A[(long)(row0 + r) * Kk + k0 + j * 8];
    }
    #pragma unroll
    for (int c = tid; c < TN * 8; c += 256) {
      int r = c >> 3, j = c & 7;
      *(float4*)&Bs[r * 64 + ((j ^ (r & 7)) << 3)] =
          *(const float4*)&Bt[(long)(col0 + r) * Kk + k0 + j * 8];
    }
    __syncthreads();
    short8 af[2][2], bf[NI][2];
    #pragma unroll
    for (int mi = 0; mi < 2; mi++) {
      int r = wr * 32 + mi * 16 + mlane;
      #pragma unroll
      for (int kk = 0; kk < 2; kk++) {
        int jx = (kk * 4 + quad) ^ (r & 7);
        af[mi][kk] = *(const short8*)&As[r * 64 + jx * 8];
      }
    }
    #pragma unroll
    for (int ni = 0; ni < NI; ni++) {
      int rn = wc * (TN / 2) + ni * 16 + mlane;
      #pragma unroll
      for (int kk = 0; kk < 2; kk++) {
        int jx = (kk * 4 + quad) ^ (rn & 7);
        bf[ni][kk] = *(const short8*)&Bs[rn * 64 + jx * 8];
      }
    }
    #pragma unroll
    for (int kk = 0; kk < 2; kk++)
      #pragma unroll
      for (int mi = 0; mi < 2; mi++)
        #pragma unroll
        for (int ni = 0; ni < NI; ni++)
          acc[mi][ni] = __builtin_amdgcn_mfma_f32_16x16x32_bf16(af[mi][kk], bf[ni][kk],
                                                                acc[mi][ni], 0, 0, 0);
    __syncthreads();
  }
  // C/D layout: col=lane&15, row=quad*4+reg  [m89-verified]
  #pragma unroll
  for (int mi = 0; mi < 2; mi++) {
    #pragma unroll
    for (int ni = 0; ni < NI; ni++) {
      int cc = col0 + wc * (TN / 2) + ni * 16 + mlane;
      #pragma unroll
      for (int i = 0; i < 4; i++) {
        int rr = row0 + wr * 32 + mi * 16 + quad * 4 + i;
        float v = acc[mi][ni][i];
        if (EPI == 1) {
          Co[(long)rr * N + cc] = v + Res[(long)rr * N + cc];
        } else if (EPI == 2) {
          if (cc < 384) CoB[(long)rr * 384 + cc] = __float2bfloat16(v);
          else          Co2B[(long)rr * 384 + (cc - 384)] = __float2bfloat16(v);
        } else {  // EPI == 3: pixel-order split; B at 0..15, C at 16..31 of BCs row
          if (cc < 176) {
            int k4 = (cc >= 132) ? 3 : (cc >= 88) ? 2 : (cc >= 44) ? 1 : 0;
            int c = cc - k4 * 44;
            int b = rr >> 12, p = rr & 4095;
            long lbase = ((long)((b << 2) + k4) << 12) + p;   // pixel order
            if (c < 12) dtsS[lbase * 12 + c] = v;
            else        BCs[lbase * 32 + (c - 12)] = v;
          }
        }
      }
    }
  }
}

// ---------------- depthwise 3x3 conv + bias + SiLU; 2x4 pixels, d-paired ----------------
__global__ __launch_bounds__(192) void k_conv(const __hip_bfloat16* __restrict__ xbufB,
                                              const float* __restrict__ cw,
                                              const float* __restrict__ cb,
                                              __hip_bfloat16* __restrict__ xcb) {
  int blk = blockIdx.x;            // 1024: b(2) x hgroup(32) x wgroup(16)
  int wg = blk & 15, hg = (blk >> 4) & 31, b = blk >> 9;
  int h0 = hg * 2, w0 = wg * 4;
  int d0 = threadIdx.x * 2;        // channel pair d0, d0+1
  float wt0[9], wt1[9];
  #pragma unroll
  for (int i = 0; i < 9; i++) { wt0[i] = cw[(long)d0 * 9 + i]; wt1[i] = cw[(long)(d0 + 1) * 9 + i]; }
  float2 bias = *(const float2*)&cb[d0];
  float v0[4][6], v1[4][6];
  #pragma unroll
  for (int r = 0; r < 4; r++) {
    int hh = h0 + r - 1;
    bool rok = (hh >= 0) && (hh < 64);
    #pragma unroll
    for (int c = 0; c < 6; c++) {
      int ww = w0 + c - 1;
      bool ok = rok && (ww >= 0) && (ww < 64);
      unsigned uv = ok ? *(const unsigned*)&xbufB[((long)(b << 12) + (hh << 6) + ww) * 384 + d0] : 0u;
      v0[r][c] = __uint_as_float(uv << 16);
      v1[r][c] = __uint_as_float(uv & 0xffff0000u);
    }
  }
  #pragma unroll
  for (int i = 0; i < 2; i++) {
    #pragma unroll
    for (int j = 0; j < 4; j++) {
      float a0 = bias.x, a1 = bias.y;
      #pragma unroll
      for (int r = 0; r < 3; r++)
        #pragma unroll
        for (int c = 0; c < 3; c++) {
          a0 += v0[i + r][j + c] * wt0[r * 3 + c];
          a1 += v1[i + r][j + c] * wt1[r * 3 + c];
        }
      float s0 = a0 / (1.f + __expf(-a0));
      float s1 = a1 / (1.f + __expf(-a1));
      __hip_bfloat16 pr[2];
      pr[0] = __float2bfloat16(s0);
      pr[1] = __float2bfloat16(s1);
      *(unsigned*)&xcb[((long)(b << 12) + ((h0 + i) << 6) + (w0 + j)) * 384 + d0] = *(unsigned*)pr;
    }
  }
}

// powers: pws[n] = r^(n+1), log-depth pairing
__device__ __forceinline__ void pow16(float r, float* pws) {
  pws[0] = r;
  #pragma unroll
  for (int n = 1; n < 16; n++) {
    int m = n + 1, c = (m + 1) / 2, f = m - c;
    pws[n] = pws[c - 1] * pws[f - 1];
  }
}

// ---------------- scan pass 0 (+dt fused): 128 segments x 32 steps ----------------
__global__ __launch_bounds__(384) void k_scan0(
    const float* __restrict__ dtsS, const float* __restrict__ BCs,
    const __hip_bfloat16* __restrict__ xcb,
    const float* __restrict__ A_logs, const float* __restrict__ dt_w,
    const float* __restrict__ dt_b,
    __half* __restrict__ dpre, __half* __restrict__ EbH, float* __restrict__ Dend) {
  int bid = blockIdx.x;
  int s = bid & 127, bk = bid >> 7;
  int k = bk & 3, b = bk >> 2;
  int d = threadIdx.x;
  float w[12];
  const float* dwp = dt_w + ((long)(k * 384) + d) * 12;
  #pragma unroll
  for (int r = 0; r < 12; r++) w[r] = dwp[r];
  float db = dt_b[k * 384 + d];
  const float* al = A_logs + ((long)(k * 384) + d) * 16;
  bool pw = true;
  float av[16];
  #pragma unroll
  for (int n = 0; n < 16; n++) {
    float a = __expf(al[n]);
    av[n] = -a;
    pw = pw && (fabsf(a - (float)(n + 1)) < 1e-3f);
  }
  float h[16];
  #pragma unroll
  for (int n = 0; n < 16; n++) h[n] = 0.f;
  float cum = 0.f;
  long bpk = (long)bk << 12;
  long bpix = (long)(b << 12);

  if (pw) {
    #pragma unroll 4
    for (int t = 0; t < 32; t++) {
      int p = dir_pix(k, s * 32 + t);
      const float4* dq = (const float4*)(dtsS + (bpk + p) * 12);
      float4 q0 = dq[0], q1 = dq[1], q2 = dq[2];
      float x = db + q0.x * w[0] + q0.y * w[1] + q0.z * w[2] + q0.w * w[3]
                   + q1.x * w[4] + q1.y * w[5] + q1.z * w[6] + q1.w * w[7]
                   + q2.x * w[8] + q2.y * w[9] + q2.z * w[10] + q2.w * w[11];
      float e = __expf(x);
      float delta = (x > 15.f) ? x : __logf(1.f + e);
      dpre[(bpk + p) * 384 + d] = __float2half(delta);
      float u = __bfloat162float(xcb[(bpix + p) * 384 + d]);
      cum += delta;
      float du = delta * u;
      float rr = __expf(-delta);
      float pws[16]; pow16(rr, pws);
      const float4* Bq = (const float4*)(BCs + (bpk + p) * 32);
      float4 b0 = Bq[0], b1 = Bq[1], b2 = Bq[2], b3 = Bq[3];
      float Bl[16] = {b0.x, b0.y, b0.z, b0.w, b1.x, b1.y, b1.z, b1.w,
                      b2.x, b2.y, b2.z, b2.w, b3.x, b3.y, b3.z, b3.w};
      #pragma unroll
      for (int n = 0; n < 16; n++) h[n] = pws[n] * h[n] + du * Bl[n];
    }
  } else {
    for (int t = 0; t < 32; t++) {
      int p = dir_pix(k, s * 32 + t);
      const float4* dq = (const float4*)(dtsS + (bpk + p) * 12);
      float4 q0 = dq[0], q1 = dq[1], q2 = dq[2];
      float x = db + q0.x * w[0] + q0.y * w[1] + q0.z * w[2] + q0.w * w[3]
                   + q1.x * w[4] + q1.y * w[5] + q1.z * w[6] + q1.w * w[7]
                   + q2.x * w[8] + q2.y * w[9] + q2.z * w[10] + q2.w * w[11];
      float e = __expf(x);
      float delta = (x > 15.f) ? x : __logf(1.f + e);
      dpre[(bpk + p) * 384 + d] = __float2half(delta);
      float u = __bfloat162float(xcb[(bpix + p) * 384 + d]);
      cum += delta;
      float du = delta * u;
      const float4* Bq = (const float4*)(BCs + (bpk + p) * 32);
      float4 b0 = Bq[0], b1 = Bq[1], b2 = Bq[2], b3 = Bq[3];
      float Bl[16] = {b0.x, b0.y, b0.z, b0.w, b1.x, b1.y, b1.z, b1.w,
                      b2.x, b2.y, b2.z, b2.w, b3.x, b3.y, b3.z, b3.w};
      #pragma unroll
      for (int n = 0; n < 16; n++) {
        float dA = __expf(delta * av[n]);
        h[n] = dA * h[n] + du * Bl[n];
      }
    }
  }
  long g = (long)bk * 128 + s;
  float4 pk[2];
  packE(h, pk);
  float4* Ep = (float4*)(EbH + g * 6144 + (long)d * 16);
  Ep[0] = pk[0];
  Ep[1] = pk[1];
  Dend[g * 384 + d] = cum;
}

// ---------------- combine: Kogge-Stone over 128 segments; pow16 trick ----------------
__global__ __launch_bounds__(128) void k_combine(__half* __restrict__ EbH,
                                                 const float* __restrict__ Dend,
                                                 const float* __restrict__ A_logs) {
  int bid = blockIdx.x;            // bk*384 + d, 3072 blocks
  int bk = bid / 384;
  int d = bid - bk * 384;
  int k = bk & 3;
  int s = threadIdx.x;             // segment 0..127
  const float* al = A_logs + ((long)(k * 384) + d) * 16;
  bool pw = true;
  float av[16];
  #pragma unroll
  for (int n = 0; n < 16; n++) {
    float a = __expf(al[n]);
    av[n] = -a;
    pw = pw && (fabsf(a - (float)(n + 1)) < 1e-3f);
  }

  long ebase = ((long)bk * 128 + s) * 6144 + (long)d * 16;
  float e[16];
  {
    const float4* Ein = (const float4*)(EbH + ebase);
    float4 pk[2] = {Ein[0], Ein[1]};
    unpackE(pk, e);
  }
  float sig = Dend[((long)bk * 128 + s) * 384 + d];

  __shared__ float sE[128][17];    // [s][0]=sigma, [s][1..16]=e
  sE[s][0] = sig;
  #pragma unroll
  for (int n = 0; n < 16; n++) sE[s][1 + n] = e[n];
  __syncthreads();

  for (int o = 1; o < 128; o <<= 1) {
    float ps = 0.f, pe[16];
    bool act = (s >= o);
    if (act) {
      ps = sE[s - o][0];
      #pragma unroll
      for (int n = 0; n < 16; n++) pe[n] = sE[s - o][1 + n];
    }
    __syncthreads();
    if (act) {
      if (pw) {
        float rc = __expf(-sig);
        float pwr[16]; pow16(rc, pwr);      // pwr[n] = exp(av[n]*sig), av[n]=-(n+1)
        #pragma unroll
        for (int n = 0; n < 16; n++) e[n] += pwr[n] * pe[n];
      } else {
        #pragma unroll
        for (int n = 0; n < 16; n++) e[n] += __expf(av[n] * sig) * pe[n];
      }
      sig += ps;
      sE[s][0] = sig;
      #pragma unroll
      for (int n = 0; n < 16; n++) sE[s][1 + n] = e[n];
    }
    __syncthreads();
  }

  float ho[16];
  if (s == 0) {
    #pragma unroll
    for (int n = 0; n < 16; n++) ho[n] = 0.f;
  } else {
    #pragma unroll
    for (int n = 0; n < 16; n++) ho[n] = sE[s - 1][1 + n];
  }
  float4 pk[2];
  packE(ho, pk);
  float4* Eo = (float4*)(EbH + ebase);
  Eo[0] = pk[0];
  Eo[1] = pk[1];
}

// ---------------- scan pass 1: full recurrence from h_in (fp16 in EbH) ----------------
// ATOMIC=0: store y bf16 into per-direction plane ybufB. ATOMIC=1: fp32 atomicAdd ysum.
template <int ATOMIC>
__global__ __launch_bounds__(384) void k_scan1(
    const __half* __restrict__ dpre, const float* __restrict__ BCs,
    const __hip_bfloat16* __restrict__ xcb,
    const float* __restrict__ A_logs, const __half* __restrict__ EbH,
    __hip_bfloat16* __restrict__ ybufB, float* __restrict__ ysum) {
  int bid = blockIdx.x;
  int s = bid & 127, bk = bid >> 7;
  int k = bk & 3, b = bk >> 2;
  int d = threadIdx.x;
  const float* al = A_logs + ((long)(k * 384) + d) * 16;
  bool pw = true;
  float av[16];
  #pragma unroll
  for (int n = 0; n < 16; n++) {
    float a = __expf(al[n]);
    av[n] = -a;
    pw = pw && (fabsf(a - (float)(n + 1)) < 1e-3f);
  }
  float h[16];
  {
    const float4* hp = (const float4*)(EbH + ((long)bk * 128 + s) * 6144 + (long)d * 16);
    float4 pk[2] = {hp[0], hp[1]};
    unpackE(pk, h);
  }
  long bpk = (long)bk << 12;
  long bpix = (long)(b << 12);

  if (pw) {
    #pragma unroll 4
    for (int t = 0; t < 32; t++) {
      int p = dir_pix(k, s * 32 + t);
      float delta = __half2float(dpre[(bpk + p) * 384 + d]);
      float u = __bfloat162float(xcb[(bpix + p) * 384 + d]);
      float du = delta * u;
      float rr = __expf(-delta);
      float pws[16]; pow16(rr, pws);
      const float4* Bq = (const float4*)(BCs + (bpk + p) * 32);
      float4 b0 = Bq[0], b1 = Bq[1], b2 = Bq[2], b3 = Bq[3];
      float Bl[16] = {b0.x, b0.y, b0.z, b0.w, b1.x, b1.y, b1.z, b1.w,
                      b2.x, b2.y, b2.z, b2.w, b3.x, b3.y, b3.z, b3.w};
      const float4* Cq = Bq + 4;
      float4 c0 = Cq[0], c1 = Cq[1], c2 = Cq[2], c3 = Cq[3];
      float Cl[16] = {c0.x, c0.y, c0.z, c0.w, c1.x, c1.y, c1.z, c1.w,
                      c2.x, c2.y, c2.z, c2.w, c3.x, c3.y, c3.z, c3.w};
      float y = 0.f;
      #pragma unroll
      for (int n = 0; n < 16; n++) { h[n] = pws[n] * h[n] + du * Bl[n]; y += h[n] * Cl[n]; }
      if (ATOMIC) atomicAdd(&ysum[(bpix + p) * 384 + d], y);
      else        ybufB[(bpk + p) * 384 + d] = __float2bfloat16(y);
    }
  } else {
    for (int t = 0; t < 32; t++) {
      int p = dir_pix(k, s * 32 + t);
      float delta = __half2float(dpre[(bpk + p) * 384 + d]);
      float u = __bfloat162float(xcb[(bpix + p) * 384 + d]);
      float du = delta * u;
      const float4* Bq = (const float4*)(BCs + (bpk + p) * 32);
      float4 b0 = Bq[0], b1 = Bq[1], b2 = Bq[2], b3 = Bq[3];
      float Bl[16] = {b0.x, b0.y, b0.z, b0.w, b1.x, b1.y, b1.z, b1.w,
                      b2.x, b2.y, b2.z, b2.w, b3.x, b3.y, b3.z, b3.w};
      const float4* Cq = Bq + 4;
      float4 c0 = Cq[0], c1 = Cq[1], c2 = Cq[2], c3 = Cq[3];
      float Cl[16] = {c0.x, c0.y, c0.z, c0.w, c1.x, c1.y, c1.z, c1.w,
                      c2.x, c2.y, c2.z, c2.w, c3.x, c3.y, c3.z, c3.w};
      float y = 0.f;
      #pragma unroll
      for (int n = 0; n < 16; n++) {
        float dA = __expf(delta * av[n]);
        h[n] = dA * h[n] + du * Bl[n];
        y += h[n] * Cl[n];
      }
      if (ATOMIC) atomicAdd(&ysum[(bpix + p) * 384 + d], y);
      else        ybufB[(bpk + p) * 384 + d] = __float2bfloat16(y);
    }
  }
}

// ---------------- merge (d-paired, 192 thr): y + D-skip + out-LN + silu(z) -> bf16 ----------------
template <int GATHER>
__global__ __launch_bounds__(192) void k_merge(const __hip_bfloat16* __restrict__ yinB,
                                               const float* __restrict__ yinF,
                                               const __hip_bfloat16* __restrict__ xcb,
                                               const __hip_bfloat16* __restrict__ zbufB,
                                               const float* __restrict__ sdsum,
                                               const float* __restrict__ g,
                                               const float* __restrict__ be,
                                               __hip_bfloat16* __restrict__ yactb) {
  int row = blockIdx.x;
  int d0 = threadIdx.x * 2;
  float v0, v1;
  if (GATHER) {
    int b = row >> 12, p = row & 4095;
    long base = ((long)(b << 2) << 12) + p;  // plane (b*4+k)*4096 + p
    v0 = 0.f; v1 = 0.f;
    #pragma unroll
    for (int pl = 0; pl < 4; pl++) {
      unsigned uv = *(const unsigned*)&yinB[(base + pl * 4096) * 384 + d0];
      v0 += __uint_as_float(uv << 16);
      v1 += __uint_as_float(uv & 0xffff0000u);
    }
  } else {
    float2 vv = *(const float2*)&yinF[(long)row * 384 + d0];
    v0 = vv.x; v1 = vv.y;
  }
  float2 sd = *(const float2*)&sdsum[d0];
  {
    unsigned uv = *(const unsigned*)&xcb[(long)row * 384 + d0];
    v0 += __uint_as_float(uv << 16) * sd.x;
    v1 += __uint_as_float(uv & 0xffff0000u) * sd.y;
  }
  float s1 = v0 + v1, s2 = v0 * v0 + v1 * v1;
  #pragma unroll
  for (int o = 32; o > 0; o >>= 1) { s1 += __shfl_xor(s1, o); s2 += __shfl_xor(s2, o); }
  __shared__ float r1[3], r2[3];
  int wv = threadIdx.x >> 6;
  if ((threadIdx.x & 63) == 0) { r1[wv] = s1; r2[wv] = s2; }
  __syncthreads();
  float S1 = r1[0] + r1[1] + r1[2];
  float S2 = r2[0] + r2[1] + r2[2];
  float mu = S1 * (1.f / 384.f);
  float var = S2 * (1.f / 384.f) - mu * mu;
  float rr = rsqrtf(var + 1e-5f);
  float2 gg = *(const float2*)&g[d0];
  float2 bb = *(const float2*)&be[d0];
  float yn0 = (v0 - mu) * rr * gg.x + bb.x;
  float yn1 = (v1 - mu) * rr * gg.y + bb.y;
  unsigned uz = *(const unsigned*)&zbufB[(long)row * 384 + d0];
  float z0 = __uint_as_float(uz << 16);
  float z1 = __uint_as_float(uz & 0xffff0000u);
  float sg0 = z0 / (1.f + __expf(-z0));
  float sg1 = z1 / (1.f + __expf(-z1));
  __hip_bfloat16 pr[2];
  pr[0] = __float2bfloat16(yn0 * sg0);
  pr[1] = __float2bfloat16(yn1 * sg1);
  *(unsigned*)&yactb[(long)row * 384 + d0] = *(unsigned*)pr;
}

extern "C" void kernel_launch(void* const* d_in, const int* in_sizes, int n_in,
                              void* d_out, int out_size, void* d_ws, size_t ws_size,
                              hipStream_t stream) {
  const float* input      = (const float*)d_in[0];
  const float* norm_g     = (const float*)d_in[1];
  const float* norm_b     = (const float*)d_in[2];
  const float* in_proj_w  = (const float*)d_in[3];
  const float* conv_w     = (const float*)d_in[4];
  const float* conv_b     = (const float*)d_in[5];
  const float* x_proj_w   = (const float*)d_in[6];
  const float* dt_w       = (const float*)d_in[7];
  const float* dt_b       = (const float*)d_in[8];
  const float* A_logs     = (const float*)d_in[9];
  const float* Ds         = (const float*)d_in[10];
  const float* out_norm_g = (const float*)d_in[11];
  const float* out_norm_b = (const float*)d_in[12];
  const float* out_proj_w = (const float*)d_in[13];
  float* out = (float*)d_out;

  // plane path total ~ 24.8M floats (~99 MB); atomic fallback ~87 MB
  bool big = ws_size >= (size_t)24789504 * 4;

  float* ws = (float*)d_ws;
  long o = 0;
  __hip_bfloat16* xnb   = (__hip_bfloat16*)(ws + o); o += 786432;   // 8192x192 bf16
  __hip_bfloat16* xbufB = (__hip_bfloat16*)(ws + o); o += 1572864;  // 8192x384 bf16
  __hip_bfloat16* zbufB = (__hip_bfloat16*)(ws + o); o += 1572864;
  __hip_bfloat16* xcb   = (__hip_bfloat16*)(ws + o); o += 1572864;
  __hip_bfloat16* Wt1   = (__hip_bfloat16*)(ws + o); o += 73728;    // 768x192 bf16
  __hip_bfloat16* Wt2   = (__hip_bfloat16*)(ws + o); o += 36864;
  __hip_bfloat16* Wt3   = (__hip_bfloat16*)(ws + o); o += 36864;
  float* sdsum          = ws + o;                    o += 512;      // Ds col-sum (384, padded)
  float* dtsS           = ws + o;                    o += 393216;   // (BK,p,12) pixel order
  float* BCs            = ws + o;                    o += 1048576;  // (BK,p,32): B|C interleaved
  __half* dpre          = (__half*)(ws + o);         o += 6291456;  // (BK,p,384) fp16 delta
  __half* EbH           = (__half*)(ws + o);         o += 3145728;  // (1024 segs, 6144) fp16
  float* Dend           = ws + o;                    o += 393216;   // (1024, 384) fp32
  __hip_bfloat16* ybufB = (__hip_bfloat16*)(ws + o);
  float* ysum           = ws + o;                    o += big ? 6291456 : 3145728;
  __hip_bfloat16* yactb = (__hip_bfloat16*)(ws + o); o += 1572864;

  k_lnpackw<<<dim3(3202), dim3(256), 0, stream>>>(input, norm_g, norm_b, xnb,
                                                  in_proj_w, x_proj_w, out_proj_w, Ds,
                                                  Wt1, Wt2, Wt3, sdsum);
  k_gemm_mfma<2, 192><<<dim3(4, 128), dim3(256), 0, stream>>>(xnb, Wt1, nullptr, nullptr, xbufB, zbufB,
                                                              nullptr, nullptr, 8192, 768, 192);
  k_conv<<<dim3(1024), dim3(192), 0, stream>>>(xbufB, conv_w, conv_b, xcb);
  k_gemm_mfma<3, 64><<<dim3(3, 128), dim3(256), 0, stream>>>(xcb, Wt2, nullptr, nullptr, nullptr, nullptr,
                                                             dtsS, BCs, 8192, 192, 384);
  k_scan0<<<dim3(1024), dim3(384), 0, stream>>>(dtsS, BCs, xcb, A_logs, dt_w, dt_b,
                                                dpre, EbH, Dend);
  k_combine<<<dim3(3072), dim3(128), 0, stream>>>(EbH, Dend, A_logs);
  if (big) {
    k_scan1<0><<<dim3(1024), dim3(384), 0, stream>>>(dpre, BCs, xcb, A_logs, EbH, ybufB, nullptr);
    k_merge<1><<<dim3(8192), dim3(192), 0, stream>>>(ybufB, nullptr, xcb, zbufB, sdsum,
                                                     out_norm_g, out_norm_b, yactb);
  } else {
    hipMemsetAsync(ysum, 0, (size_t)3145728 * 4, stream);
    k_scan1<1><<<dim3(1024), dim3(384), 0, stream>>>(dpre, BCs, xcb, A_logs, EbH, nullptr, ysum);
    k_merge<0><<<dim3(8192), dim3(192), 0, stream>>>(nullptr, ysum, xcb, zbufB, sdsum,
                                                     out_norm_g, out_norm_b, yactb);
  }
  k_gemm_mfma<1, 64><<<dim3(3, 128), dim3(256), 0, stream>>>(yactb, Wt3, input, out, nullptr, nullptr,
                                                             nullptr, nullptr, 8192, 192, 384);
}